// Round 5
// baseline (1126.975 us; speedup 1.0000x reference)
//
#include <hip/hip_runtime.h>
#include <hip/hip_bf16.h>
#include <math.h>

#define T_LEN 2048
#define EMB   512
#define NHEAD 8
#define HDIM  64
#define BHEADS 32
#define USEL  40

// ---------------------------------------------------------------------------
// Kernel A: fused QKV projection (fp32 VALU GEMM).
// Y = X @ W^T + b (q additionally *0.125), written per-head [bh][t][d].
// Block: 64 M x 128 N tile; thread: 8 M x 4 N register outer product.
// ---------------------------------------------------------------------------
__global__ __launch_bounds__(256)
void qkv_proj_kernel(const float* __restrict__ X,
                     const float* __restrict__ Wq, const float* __restrict__ bq,
                     const float* __restrict__ Wk, const float* __restrict__ bk,
                     const float* __restrict__ Wv, const float* __restrict__ bv,
                     float* __restrict__ qo, float* __restrict__ ko, float* __restrict__ vo)
{
    alignas(16) __shared__ float Xs[64 * 64];    // [k][m]
    alignas(16) __shared__ float Wt[64 * 128];   // [k][n]

    const int z = blockIdx.z;
    const float* W; const float* bias; float* dst; float scale;
    if (z == 0)      { W = Wq; bias = bq; dst = qo; scale = 0.125f; }
    else if (z == 1) { W = Wk; bias = bk; dst = ko; scale = 1.0f;   }
    else             { W = Wv; bias = bv; dst = vo; scale = 1.0f;   }

    const int tid = threadIdx.x;
    const int m0 = blockIdx.x * 64;
    const int n0 = blockIdx.y * 128;
    const int ti = tid >> 5, tj = tid & 31;

    float acc[8][4];
    #pragma unroll
    for (int i = 0; i < 8; ++i)
        #pragma unroll
        for (int j = 0; j < 4; ++j) acc[i][j] = 0.0f;

    for (int kc = 0; kc < EMB; kc += 64) {
        __syncthreads();
        #pragma unroll
        for (int s = 0; s < 4; ++s) {
            int u = tid + 256 * s;          // 0..1023
            int mm = u & 63, c4 = u >> 6;   // c4: 0..15
            float4 f = *(const float4*)&X[(m0 + mm) * EMB + kc + c4 * 4];
            Xs[(c4 * 4 + 0) * 64 + mm] = f.x;
            Xs[(c4 * 4 + 1) * 64 + mm] = f.y;
            Xs[(c4 * 4 + 2) * 64 + mm] = f.z;
            Xs[(c4 * 4 + 3) * 64 + mm] = f.w;
        }
        #pragma unroll
        for (int s = 0; s < 8; ++s) {
            int u = tid + 256 * s;          // 0..2047
            int nn = u & 127, c4 = u >> 7;  // c4: 0..15
            float4 f = *(const float4*)&W[(n0 + nn) * EMB + kc + c4 * 4];
            Wt[(c4 * 4 + 0) * 128 + nn] = f.x;
            Wt[(c4 * 4 + 1) * 128 + nn] = f.y;
            Wt[(c4 * 4 + 2) * 128 + nn] = f.z;
            Wt[(c4 * 4 + 3) * 128 + nn] = f.w;
        }
        __syncthreads();

        #pragma unroll 8
        for (int k = 0; k < 64; ++k) {
            float4 wv = *(const float4*)&Wt[k * 128 + tj * 4];
            float4 xa = *(const float4*)&Xs[k * 64 + ti * 8];
            float4 xb = *(const float4*)&Xs[k * 64 + ti * 8 + 4];
            float xv[8] = {xa.x, xa.y, xa.z, xa.w, xb.x, xb.y, xb.z, xb.w};
            #pragma unroll
            for (int i = 0; i < 8; ++i) {
                acc[i][0] = fmaf(xv[i], wv.x, acc[i][0]);
                acc[i][1] = fmaf(xv[i], wv.y, acc[i][1]);
                acc[i][2] = fmaf(xv[i], wv.z, acc[i][2]);
                acc[i][3] = fmaf(xv[i], wv.w, acc[i][3]);
            }
        }
    }

    const int n = n0 + tj * 4;
    const int h = n >> 6, d = n & 63;
    float4 bf4 = *(const float4*)&bias[n];
    #pragma unroll
    for (int i = 0; i < 8; ++i) {
        int m = m0 + ti * 8 + i;
        int b = m >> 11, t = m & 2047;
        float4 v4;
        v4.x = (acc[i][0] + bf4.x) * scale;
        v4.y = (acc[i][1] + bf4.y) * scale;
        v4.z = (acc[i][2] + bf4.z) * scale;
        v4.w = (acc[i][3] + bf4.w) * scale;
        *(float4*)&dst[((size_t)((b * NHEAD + h) * T_LEN + t)) * HDIM + d] = v4;
    }
}

// ---------------------------------------------------------------------------
// Kernel B1: maskf[t] = 0 if t sampled else -inf (shared across all bh).
// ---------------------------------------------------------------------------
__global__ void build_mask_kernel(const int* __restrict__ idxs, int n, float* __restrict__ maskf)
{
    int tid = threadIdx.x;
    for (int j = tid; j < T_LEN; j += 256) maskf[j] = -INFINITY;
    __syncthreads();
    for (int i = tid; i < n; i += 256) maskf[idxs[i] & (T_LEN - 1)] = 0.0f;
}

// ---------------------------------------------------------------------------
// Kernel B2: ksum[bh][d] = sum over sampled (with multiplicity) of k rows;
//            vmean[bh][d] = mean_t v.
// ---------------------------------------------------------------------------
__global__ __launch_bounds__(256)
void ksum_vmean_kernel(const int* __restrict__ idxs, int n,
                       const float* __restrict__ k, const float* __restrict__ v,
                       float* __restrict__ ksum, float* __restrict__ vmean)
{
    __shared__ float pk[256], pv[256];
    const int bh = blockIdx.x, tid = threadIdx.x;
    const int chunk = tid >> 6, lane = tid & 63;
    const float* kb = k + (size_t)bh * T_LEN * HDIM;
    const float* vb = v + (size_t)bh * T_LEN * HDIM;
    float ak = 0.f, av = 0.f;
    for (int i = chunk; i < n; i += 4) ak += kb[(idxs[i] & (T_LEN - 1)) * HDIM + lane];
    for (int t = chunk; t < T_LEN; t += 4) av += vb[t * HDIM + lane];
    pk[chunk * 64 + lane] = ak;
    pv[chunk * 64 + lane] = av;
    __syncthreads();
    if (tid < 64) {
        ksum[bh * 64 + tid]  = pk[tid] + pk[64 + tid] + pk[128 + tid] + pk[192 + tid];
        vmean[bh * 64 + tid] = (pv[tid] + pv[64 + tid] + pv[128 + tid] + pv[192 + tid]) * (1.0f / 2048.0f);
    }
}

// ---------------------------------------------------------------------------
// Kernel C: sparsity scan (fp32). Block: 64 queries x 2048 keys in 128-tiles.
// sparsity[bh][q] = max_{sampled k}(q.k) - (q.ksum)/2048
// ---------------------------------------------------------------------------
__global__ __launch_bounds__(256)
void sparsity_scan_kernel(const float* __restrict__ q, const float* __restrict__ k,
                          const float* __restrict__ ksum, const float* __restrict__ maskf,
                          float* __restrict__ spars)
{
    alignas(16) __shared__ float qs[64 * 64];   // [d][qq]
    alignas(16) __shared__ float ks[64 * 128];  // [d][kk] (reused as reduce buffer)
    alignas(16) __shared__ float msk[128];
    alignas(16) __shared__ float ksm[64];

    const int tid = threadIdx.x;
    const int bh = blockIdx.y;
    const int q0 = blockIdx.x * 64;
    const int ti = tid >> 5, tj = tid & 31;

    const float* qb = q + ((size_t)bh * T_LEN + q0) * HDIM;
    const float* kb = k + (size_t)bh * T_LEN * HDIM;

    #pragma unroll
    for (int s = 0; s < 4; ++s) {
        int u = tid + 256 * s;          // 0..1023
        int qq = u & 63, c4 = u >> 6;   // c4: 0..15
        float4 f = *(const float4*)&qb[qq * HDIM + c4 * 4];
        qs[(c4 * 4 + 0) * 64 + qq] = f.x;
        qs[(c4 * 4 + 1) * 64 + qq] = f.y;
        qs[(c4 * 4 + 2) * 64 + qq] = f.z;
        qs[(c4 * 4 + 3) * 64 + qq] = f.w;
    }
    if (tid < 64) ksm[tid] = ksum[bh * 64 + tid];

    float vmax[8];
    #pragma unroll
    for (int i = 0; i < 8; ++i) vmax[i] = -INFINITY;

    for (int kt = 0; kt < 16; ++kt) {
        __syncthreads();
        #pragma unroll
        for (int s = 0; s < 8; ++s) {
            int u = tid + 256 * s;          // 0..2047
            int kk = u & 127, c4 = u >> 7;  // c4: 0..15
            float4 f = *(const float4*)&kb[(kt * 128 + kk) * HDIM + c4 * 4];
            ks[(c4 * 4 + 0) * 128 + kk] = f.x;
            ks[(c4 * 4 + 1) * 128 + kk] = f.y;
            ks[(c4 * 4 + 2) * 128 + kk] = f.z;
            ks[(c4 * 4 + 3) * 128 + kk] = f.w;
        }
        if (tid < 128) msk[tid] = maskf[kt * 128 + tid];
        __syncthreads();

        float dot[8][4];
        #pragma unroll
        for (int i = 0; i < 8; ++i)
            #pragma unroll
            for (int j = 0; j < 4; ++j) dot[i][j] = 0.0f;

        #pragma unroll 8
        for (int d = 0; d < 64; ++d) {
            float4 kv = *(const float4*)&ks[d * 128 + tj * 4];
            float4 qa = *(const float4*)&qs[d * 64 + ti * 8];
            float4 qb4 = *(const float4*)&qs[d * 64 + ti * 8 + 4];
            float qv[8] = {qa.x, qa.y, qa.z, qa.w, qb4.x, qb4.y, qb4.z, qb4.w};
            #pragma unroll
            for (int i = 0; i < 8; ++i) {
                dot[i][0] = fmaf(qv[i], kv.x, dot[i][0]);
                dot[i][1] = fmaf(qv[i], kv.y, dot[i][1]);
                dot[i][2] = fmaf(qv[i], kv.z, dot[i][2]);
                dot[i][3] = fmaf(qv[i], kv.w, dot[i][3]);
            }
        }
        #pragma unroll
        for (int j = 0; j < 4; ++j) {
            float mj = msk[tj * 4 + j];  // 0 or -inf
            #pragma unroll
            for (int i = 0; i < 8; ++i)
                vmax[i] = fmaxf(vmax[i], dot[i][j] + mj);
        }
    }
    __syncthreads();

    float* red = ks;
    #pragma unroll
    for (int i = 0; i < 8; ++i) red[(ti * 8 + i) * 33 + tj] = vmax[i];
    __syncthreads();
    if (tid < 64) {
        int qq = tid;
        float m = -INFINITY;
        #pragma unroll
        for (int j = 0; j < 32; ++j) m = fmaxf(m, red[qq * 33 + j]);
        float sdot = 0.f;
        #pragma unroll
        for (int d = 0; d < 64; ++d) sdot = fmaf(qs[d * 64 + qq], ksm[d], sdot);
        spars[bh * T_LEN + q0 + qq] = m - sdot * (1.0f / 2048.0f);
    }
}

// ---------------------------------------------------------------------------
// Kernel D: top-40 per bh by iterative argmax (ties -> smaller index).
// NaN-safe: bi starts at 0 and the winning index is masked to [0,2047].
// ---------------------------------------------------------------------------
__global__ __launch_bounds__(256)
void topk_kernel(const float* __restrict__ spars, int* __restrict__ topi)
{
    __shared__ float vals[T_LEN];
    __shared__ float rv[256];
    __shared__ int   ri[256];
    const int bh = blockIdx.x, tid = threadIdx.x;
    for (int j = tid; j < T_LEN; j += 256) vals[j] = spars[bh * T_LEN + j];
    __syncthreads();
    for (int it = 0; it < USEL; ++it) {
        float bv = -INFINITY; int bi = 0;
        #pragma unroll
        for (int jj = 0; jj < 8; ++jj) {
            int j = tid * 8 + jj;
            float vv = vals[j];
            if (vv > bv) { bv = vv; bi = j; }
        }
        rv[tid] = bv; ri[tid] = bi;
        __syncthreads();
        for (int s = 128; s > 0; s >>= 1) {
            if (tid < s) {
                float ov = rv[tid + s]; int oi = ri[tid + s];
                if (ov > rv[tid] || (ov == rv[tid] && oi < ri[tid])) { rv[tid] = ov; ri[tid] = oi; }
            }
            __syncthreads();
        }
        if (tid == 0) {
            int win = ri[0] & (T_LEN - 1);
            topi[bh * USEL + it] = win;
            vals[win] = -INFINITY;
        }
        __syncthreads();
    }
}

// ---------------------------------------------------------------------------
// Kernel E: softmax attention for the 40 selected queries per bh.
// ---------------------------------------------------------------------------
__global__ __launch_bounds__(256)
void sel_attn_kernel(const float* __restrict__ q, const float* __restrict__ k,
                     const float* __restrict__ v, const int* __restrict__ topi,
                     float* __restrict__ attn)
{
    alignas(16) __shared__ float qv[64];
    alignas(16) __shared__ float sc[T_LEN];
    __shared__ float red[256];
    __shared__ float part[256];

    const int u = blockIdx.x, bh = blockIdx.y, tid = threadIdx.x;
    const int tq = topi[bh * USEL + u] & (T_LEN - 1);
    if (tid < 64) qv[tid] = q[((size_t)bh * T_LEN + tq) * HDIM + tid];
    __syncthreads();

    const float* kb = k + (size_t)bh * T_LEN * HDIM;
    const float* vb = v + (size_t)bh * T_LEN * HDIM;

    float lmax = -INFINITY;
    #pragma unroll
    for (int s = 0; s < 8; ++s) {
        int t = tid + 256 * s;
        const float* kr = kb + t * HDIM;
        float acc = 0.f;
        #pragma unroll
        for (int d4 = 0; d4 < 16; ++d4) {
            float4 kf = *(const float4*)&kr[d4 * 4];
            float4 qf = *(const float4*)&qv[d4 * 4];
            acc = fmaf(kf.x, qf.x, acc);
            acc = fmaf(kf.y, qf.y, acc);
            acc = fmaf(kf.z, qf.z, acc);
            acc = fmaf(kf.w, qf.w, acc);
        }
        sc[t] = acc;
        lmax = fmaxf(lmax, acc);
    }
    red[tid] = lmax;
    __syncthreads();
    for (int s = 128; s > 0; s >>= 1) {
        if (tid < s) red[tid] = fmaxf(red[tid], red[tid + s]);
        __syncthreads();
    }
    float m = red[0];
    __syncthreads();

    float lsum = 0.f;
    #pragma unroll
    for (int s = 0; s < 8; ++s) {
        int t = tid + 256 * s;
        float p = __expf(sc[t] - m);
        sc[t] = p;
        lsum += p;
    }
    red[tid] = lsum;
    __syncthreads();
    for (int s = 128; s > 0; s >>= 1) {
        if (tid < s) red[tid] += red[tid + s];
        __syncthreads();
    }
    float l = red[0];

    const int w = tid >> 6, lane = tid & 63;
    float acc = 0.f;
    #pragma unroll 4
    for (int it = 0; it < 512; ++it) {
        int t = w * 512 + it;
        acc = fmaf(sc[t], vb[t * HDIM + lane], acc);
    }
    part[w * 64 + lane] = acc;
    __syncthreads();
    if (tid < 64) {
        float tot = part[tid] + part[64 + tid] + part[128 + tid] + part[192 + tid];
        attn[((size_t)bh * USEL + u) * HDIM + tid] = tot / l;
    }
}

// ---------------------------------------------------------------------------
// Kernel F1: fill context (B,T,E layout, fp32) with per-head vmean.
// ---------------------------------------------------------------------------
__global__ __launch_bounds__(256)
void ctx_fill_kernel(const float* __restrict__ vmean, float* __restrict__ ctx)
{
    int flat = blockIdx.x * 256 + threadIdx.x;
    int d = flat & 63, h = (flat >> 6) & 7, b = flat >> 20;
    int bh = (b << 3) | h;
    ctx[flat] = vmean[bh * 64 + d];
}

// ---------------------------------------------------------------------------
// Kernel F2: scatter attn rows into context at top_idx positions.
// ---------------------------------------------------------------------------
__global__ void ctx_scatter_kernel(const float* __restrict__ attn, const int* __restrict__ topi,
                                   float* __restrict__ ctx)
{
    const int u = blockIdx.x, bh = blockIdx.y, d = threadIdx.x;
    const int b = bh >> 3, h = bh & 7;
    const int t = topi[bh * USEL + u] & (T_LEN - 1);
    ctx[(size_t)(b * T_LEN + t) * EMB + h * 64 + d] =
        attn[((size_t)bh * USEL + u) * HDIM + d];
}

// ---------------------------------------------------------------------------
// Kernel G: out = ctx @ Wo^T + bo (fp32 VALU GEMM, same tiling as Kernel A).
// ---------------------------------------------------------------------------
__global__ __launch_bounds__(256)
void out_proj_kernel(const float* __restrict__ A, const float* __restrict__ Wo,
                     const float* __restrict__ bo, float* __restrict__ out)
{
    alignas(16) __shared__ float Xs[64 * 64];    // [k][m]
    alignas(16) __shared__ float Wt[64 * 128];   // [k][n]

    const int tid = threadIdx.x;
    const int m0 = blockIdx.x * 64;
    const int n0 = blockIdx.y * 128;
    const int ti = tid >> 5, tj = tid & 31;

    float acc[8][4];
    #pragma unroll
    for (int i = 0; i < 8; ++i)
        #pragma unroll
        for (int j = 0; j < 4; ++j) acc[i][j] = 0.0f;

    for (int kc = 0; kc < EMB; kc += 64) {
        __syncthreads();
        #pragma unroll
        for (int s = 0; s < 4; ++s) {
            int u = tid + 256 * s;
            int mm = u & 63, c4 = u >> 6;
            float4 f = *(const float4*)&A[(m0 + mm) * EMB + kc + c4 * 4];
            Xs[(c4 * 4 + 0) * 64 + mm] = f.x;
            Xs[(c4 * 4 + 1) * 64 + mm] = f.y;
            Xs[(c4 * 4 + 2) * 64 + mm] = f.z;
            Xs[(c4 * 4 + 3) * 64 + mm] = f.w;
        }
        #pragma unroll
        for (int s = 0; s < 8; ++s) {
            int u = tid + 256 * s;
            int nn = u & 127, c4 = u >> 7;
            float4 f = *(const float4*)&Wo[(n0 + nn) * EMB + kc + c4 * 4];
            Wt[(c4 * 4 + 0) * 128 + nn] = f.x;
            Wt[(c4 * 4 + 1) * 128 + nn] = f.y;
            Wt[(c4 * 4 + 2) * 128 + nn] = f.z;
            Wt[(c4 * 4 + 3) * 128 + nn] = f.w;
        }
        __syncthreads();

        #pragma unroll 8
        for (int k = 0; k < 64; ++k) {
            float4 wv = *(const float4*)&Wt[k * 128 + tj * 4];
            float4 xa = *(const float4*)&Xs[k * 64 + ti * 8];
            float4 xb = *(const float4*)&Xs[k * 64 + ti * 8 + 4];
            float xv[8] = {xa.x, xa.y, xa.z, xa.w, xb.x, xb.y, xb.z, xb.w};
            #pragma unroll
            for (int i = 0; i < 8; ++i) {
                acc[i][0] = fmaf(xv[i], wv.x, acc[i][0]);
                acc[i][1] = fmaf(xv[i], wv.y, acc[i][1]);
                acc[i][2] = fmaf(xv[i], wv.z, acc[i][2]);
                acc[i][3] = fmaf(xv[i], wv.w, acc[i][3]);
            }
        }
    }

    const int n = n0 + tj * 4;
    float4 bf4 = *(const float4*)&bo[n];
    #pragma unroll
    for (int i = 0; i < 8; ++i) {
        int m = m0 + ti * 8 + i;
        float4 v4;
        v4.x = acc[i][0] + bf4.x;
        v4.y = acc[i][1] + bf4.y;
        v4.z = acc[i][2] + bf4.z;
        v4.w = acc[i][3] + bf4.w;
        *(float4*)&out[(size_t)m * EMB + n] = v4;
    }
}

// ---------------------------------------------------------------------------
// Diagnostic: if ws_size is too small, report it via d_out (absmax ~= MiB).
// ---------------------------------------------------------------------------
__global__ __launch_bounds__(256)
void ws_diag_kernel(float* __restrict__ out, int n, float mib)
{
    int flat = blockIdx.x * 256 + threadIdx.x;
    if (flat < n) out[flat] = mib;
}

// ---------------------------------------------------------------------------
extern "C" void kernel_launch(void* const* d_in, const int* in_sizes, int n_in,
                              void* d_out, int out_size, void* d_ws, size_t ws_size,
                              hipStream_t stream)
{
    // Evidence across rounds 0-4 pins: fp32 inputs/outputs, documented DICT
    // order (hidden, index, Wq,bq, Wk,bk, Wv,bv, Wo,bo). R1/R2 crashes were
    // NaN-spars -> wild topk index (fixed by clamps), NOT input ordering.
    // Bind by size, mapping same-size tensors in ENCOUNTER (=dict) order.
    const float* X = nullptr; const int* idxs = nullptr;
    const float* Wseen[4] = {nullptr, nullptr, nullptr, nullptr};
    const float* bseen[4] = {nullptr, nullptr, nullptr, nullptr};
    int nw = 0, nb = 0, u_part = 2048;
    for (int i = 0; i < n_in; ++i) {
        int sz = in_sizes[i];
        if (sz == EMB * EMB * 16) { if (!X) X = (const float*)d_in[i]; }
        else if (sz == T_LEN)     { if (!idxs) { idxs = (const int*)d_in[i]; u_part = sz; } }
        else if (sz == EMB * EMB) { if (nw < 4) Wseen[nw++] = (const float*)d_in[i]; }
        else if (sz == EMB)       { if (nb < 4) bseen[nb++] = (const float*)d_in[i]; }
    }
    if (!X || !idxs || nw < 4 || nb < 4) {
        X = (const float*)d_in[0]; idxs = (const int*)d_in[1];
        Wseen[0] = (const float*)d_in[2]; bseen[0] = (const float*)d_in[3];
        Wseen[1] = (const float*)d_in[4]; bseen[1] = (const float*)d_in[5];
        Wseen[2] = (const float*)d_in[6]; bseen[2] = (const float*)d_in[7];
        Wseen[3] = (const float*)d_in[8]; bseen[3] = (const float*)d_in[9];
        u_part = in_sizes[1];
    }
    // Encounter order == dict order: Wq, Wk, Wv, Wo.
    const float *Wq = Wseen[0], *Wk = Wseen[1], *Wv = Wseen[2], *Wo = Wseen[3];
    const float *bq = bseen[0], *bk = bseen[1], *bv = bseen[2], *bo = bseen[3];

    // Workspace (peak 50,951,168 B):
    //   [0, 48MB):  qw / kw / vw (fp32, dead after sel_attn)
    //   [0, 16MB):  ctx fp32 (overlaid on qw after sel_attn)
    //   [48MB, +):  spars, maskf, ksum, vmean, attn, topi
    const size_t NEED = 50951168ULL;
    if (ws_size < NEED) {
        ws_diag_kernel<<<(out_size + 255) / 256, 256, 0, stream>>>(
            (float*)d_out, out_size, (float)(ws_size >> 20));
        return;
    }

    float* ws    = (float*)d_ws;
    float* qw    = ws;                   // 32*2048*64 fp32
    float* kw    = qw + 4194304;
    float* vw    = kw + 4194304;
    float* spars = vw + 4194304;         // 32*2048
    float* maskf = spars + 65536;        // 2048
    float* ksum  = maskf + 2048;         // 32*64
    float* vmean = ksum + 2048;          // 32*64
    float* attn  = vmean + 2048;         // 32*40*64
    int*   topi  = (int*)(attn + 81920); // 32*40
    float* ctx   = (float*)d_ws;         // 8192*512 fp32, overlay on qw

    qkv_proj_kernel<<<dim3(128, 4, 3), 256, 0, stream>>>(X, Wq, bq, Wk, bk, Wv, bv, qw, kw, vw);
    build_mask_kernel<<<1, 256, 0, stream>>>(idxs, u_part, maskf);
    ksum_vmean_kernel<<<32, 256, 0, stream>>>(idxs, u_part, kw, vw, ksum, vmean);
    sparsity_scan_kernel<<<dim3(32, 32), 256, 0, stream>>>(qw, kw, ksum, maskf, spars);
    topk_kernel<<<32, 256, 0, stream>>>(spars, topi);
    sel_attn_kernel<<<dim3(USEL, BHEADS), 256, 0, stream>>>(qw, kw, vw, topi, attn);
    // qw dead from here; ctx takes over that memory.
    ctx_fill_kernel<<<16384, 256, 0, stream>>>(vmean, ctx);
    ctx_scatter_kernel<<<dim3(USEL, BHEADS), 64, 0, stream>>>(attn, topi, ctx);
    out_proj_kernel<<<dim3(128, 4), 256, 0, stream>>>(ctx, Wo, bo, (float*)d_out);
}

// Round 6
// 805.174 us; speedup vs baseline: 1.3997x; 1.3997x over previous
//
#include <hip/hip_runtime.h>
#include <hip/hip_bf16.h>
#include <math.h>

#define T_LEN 2048
#define EMB   512
#define NHEAD 8
#define HDIM  64
#define BHEADS 32
#define USEL  40

// ---------------------------------------------------------------------------
// Kernel A: fused QKV projection (fp32 VALU GEMM).
// Y = X @ W^T + b (q additionally *0.125), written per-head [bh][t][d].
// ---------------------------------------------------------------------------
__global__ __launch_bounds__(256)
void qkv_proj_kernel(const float* __restrict__ X,
                     const float* __restrict__ Wq, const float* __restrict__ bq,
                     const float* __restrict__ Wk, const float* __restrict__ bk,
                     const float* __restrict__ Wv, const float* __restrict__ bv,
                     float* __restrict__ qo, float* __restrict__ ko, float* __restrict__ vo)
{
    alignas(16) __shared__ float Xs[64 * 64];    // [k][m]
    alignas(16) __shared__ float Wt[64 * 128];   // [k][n]

    const int z = blockIdx.z;
    const float* W; const float* bias; float* dst; float scale;
    if (z == 0)      { W = Wq; bias = bq; dst = qo; scale = 0.125f; }
    else if (z == 1) { W = Wk; bias = bk; dst = ko; scale = 1.0f;   }
    else             { W = Wv; bias = bv; dst = vo; scale = 1.0f;   }

    const int tid = threadIdx.x;
    const int m0 = blockIdx.x * 64;
    const int n0 = blockIdx.y * 128;
    const int ti = tid >> 5, tj = tid & 31;

    float acc[8][4];
    #pragma unroll
    for (int i = 0; i < 8; ++i)
        #pragma unroll
        for (int j = 0; j < 4; ++j) acc[i][j] = 0.0f;

    for (int kc = 0; kc < EMB; kc += 64) {
        __syncthreads();
        #pragma unroll
        for (int s = 0; s < 4; ++s) {
            int u = tid + 256 * s;          // 0..1023
            int mm = u & 63, c4 = u >> 6;   // c4: 0..15
            float4 f = *(const float4*)&X[(m0 + mm) * EMB + kc + c4 * 4];
            Xs[(c4 * 4 + 0) * 64 + mm] = f.x;
            Xs[(c4 * 4 + 1) * 64 + mm] = f.y;
            Xs[(c4 * 4 + 2) * 64 + mm] = f.z;
            Xs[(c4 * 4 + 3) * 64 + mm] = f.w;
        }
        #pragma unroll
        for (int s = 0; s < 8; ++s) {
            int u = tid + 256 * s;          // 0..2047
            int nn = u & 127, c4 = u >> 7;  // c4: 0..15
            float4 f = *(const float4*)&W[(n0 + nn) * EMB + kc + c4 * 4];
            Wt[(c4 * 4 + 0) * 128 + nn] = f.x;
            Wt[(c4 * 4 + 1) * 128 + nn] = f.y;
            Wt[(c4 * 4 + 2) * 128 + nn] = f.z;
            Wt[(c4 * 4 + 3) * 128 + nn] = f.w;
        }
        __syncthreads();

        #pragma unroll 8
        for (int k = 0; k < 64; ++k) {
            float4 wv = *(const float4*)&Wt[k * 128 + tj * 4];
            float4 xa = *(const float4*)&Xs[k * 64 + ti * 8];
            float4 xb = *(const float4*)&Xs[k * 64 + ti * 8 + 4];
            float xv[8] = {xa.x, xa.y, xa.z, xa.w, xb.x, xb.y, xb.z, xb.w};
            #pragma unroll
            for (int i = 0; i < 8; ++i) {
                acc[i][0] = fmaf(xv[i], wv.x, acc[i][0]);
                acc[i][1] = fmaf(xv[i], wv.y, acc[i][1]);
                acc[i][2] = fmaf(xv[i], wv.z, acc[i][2]);
                acc[i][3] = fmaf(xv[i], wv.w, acc[i][3]);
            }
        }
    }

    const int n = n0 + tj * 4;
    const int h = n >> 6, d = n & 63;
    float4 bf4 = *(const float4*)&bias[n];
    #pragma unroll
    for (int i = 0; i < 8; ++i) {
        int m = m0 + ti * 8 + i;
        int b = m >> 11, t = m & 2047;
        float4 v4;
        v4.x = (acc[i][0] + bf4.x) * scale;
        v4.y = (acc[i][1] + bf4.y) * scale;
        v4.z = (acc[i][2] + bf4.z) * scale;
        v4.w = (acc[i][3] + bf4.w) * scale;
        *(float4*)&dst[((size_t)((b * NHEAD + h) * T_LEN + t)) * HDIM + d] = v4;
    }
}

// ---------------------------------------------------------------------------
// Kernel B1: count[t] = multiplicity of t in index_sample (LDS atomics, 1 blk).
// ---------------------------------------------------------------------------
__global__ __launch_bounds__(256)
void count_kernel(const int* __restrict__ idxs, int n, int* __restrict__ count)
{
    __shared__ int cnt[T_LEN];
    const int tid = threadIdx.x;
    for (int j = tid; j < T_LEN; j += 256) cnt[j] = 0;
    __syncthreads();
    for (int i = tid; i < n; i += 256) atomicAdd(&cnt[idxs[i] & (T_LEN - 1)], 1);
    __syncthreads();
    for (int j = tid; j < T_LEN; j += 256) count[j] = cnt[j];
}

// ---------------------------------------------------------------------------
// Kernel B2a: partial ksum/vsum per (bh, slice of 256 t). Coalesced float4
// streaming (no gather): ksum = sum_t count[t]*k[t], vsum = sum_t v[t].
// grid (8, 32), 256 threads. Deterministic (fixed order), no atomics.
// ---------------------------------------------------------------------------
__global__ __launch_bounds__(256)
void ksum_vmean_part_kernel(const int* __restrict__ count,
                            const float* __restrict__ k, const float* __restrict__ v,
                            float* __restrict__ kpart, float* __restrict__ vpart)
{
    __shared__ int cs[256];
    alignas(16) __shared__ float rk[16 * 64];
    alignas(16) __shared__ float rv[16 * 64];

    const int sl = blockIdx.x, bh = blockIdx.y, tid = threadIdx.x;
    const int f4 = tid & 15, tg = tid >> 4;   // f4: float4 index in row; tg: t-group
    const int t0 = sl * 256;

    cs[tid] = count[t0 + tid];
    __syncthreads();

    const float4* k4 = (const float4*)(k + (size_t)bh * T_LEN * HDIM) + t0 * 16;
    const float4* v4 = (const float4*)(v + (size_t)bh * T_LEN * HDIM) + t0 * 16;

    float4 ak = {0.f, 0.f, 0.f, 0.f}, av = {0.f, 0.f, 0.f, 0.f};
    #pragma unroll
    for (int s = 0; s < 16; ++s) {
        int t = tg + s * 16;
        float c = (float)cs[t];
        float4 kf = k4[t * 16 + f4];
        float4 vf = v4[t * 16 + f4];
        ak.x = fmaf(c, kf.x, ak.x); ak.y = fmaf(c, kf.y, ak.y);
        ak.z = fmaf(c, kf.z, ak.z); ak.w = fmaf(c, kf.w, ak.w);
        av.x += vf.x; av.y += vf.y; av.z += vf.z; av.w += vf.w;
    }
    *(float4*)&rk[tg * 64 + f4 * 4] = ak;
    *(float4*)&rv[tg * 64 + f4 * 4] = av;
    __syncthreads();

    if (tid < 64) {
        float sk = 0.f, sv = 0.f;
        #pragma unroll
        for (int g = 0; g < 16; ++g) { sk += rk[g * 64 + tid]; sv += rv[g * 64 + tid]; }
        kpart[((size_t)bh * 8 + sl) * 64 + tid] = sk;
        vpart[((size_t)bh * 8 + sl) * 64 + tid] = sv;
    }
}

// ---------------------------------------------------------------------------
// Kernel B2b: reduce 8 slice-partials -> ksum[bh][d], vmean[bh][d].
// ---------------------------------------------------------------------------
__global__ __launch_bounds__(64)
void ksum_vmean_reduce_kernel(const float* __restrict__ kpart, const float* __restrict__ vpart,
                              float* __restrict__ ksum, float* __restrict__ vmean)
{
    const int bh = blockIdx.x, d = threadIdx.x;
    float sk = 0.f, sv = 0.f;
    #pragma unroll
    for (int sl = 0; sl < 8; ++sl) {
        sk += kpart[((size_t)bh * 8 + sl) * 64 + d];
        sv += vpart[((size_t)bh * 8 + sl) * 64 + d];
    }
    ksum[bh * 64 + d]  = sk;
    vmean[bh * 64 + d] = sv * (1.0f / 2048.0f);
}

// ---------------------------------------------------------------------------
// Kernel C: sparsity scan (fp32). Block: 64 queries x 2048 keys in 128-tiles.
// sparsity[bh][q] = max_{sampled k}(q.k) - (q.ksum)/2048. Mask from count.
// ---------------------------------------------------------------------------
__global__ __launch_bounds__(256)
void sparsity_scan_kernel(const float* __restrict__ q, const float* __restrict__ k,
                          const float* __restrict__ ksum, const int* __restrict__ count,
                          float* __restrict__ spars)
{
    alignas(16) __shared__ float qs[64 * 64];   // [d][qq]
    alignas(16) __shared__ float ks[64 * 128];  // [d][kk] (reused as reduce buffer)
    alignas(16) __shared__ float msk[128];
    alignas(16) __shared__ float ksm[64];

    const int tid = threadIdx.x;
    const int bh = blockIdx.y;
    const int q0 = blockIdx.x * 64;
    const int ti = tid >> 5, tj = tid & 31;

    const float* qb = q + ((size_t)bh * T_LEN + q0) * HDIM;
    const float* kb = k + (size_t)bh * T_LEN * HDIM;

    #pragma unroll
    for (int s = 0; s < 4; ++s) {
        int u = tid + 256 * s;          // 0..1023
        int qq = u & 63, c4 = u >> 6;   // c4: 0..15
        float4 f = *(const float4*)&qb[qq * HDIM + c4 * 4];
        qs[(c4 * 4 + 0) * 64 + qq] = f.x;
        qs[(c4 * 4 + 1) * 64 + qq] = f.y;
        qs[(c4 * 4 + 2) * 64 + qq] = f.z;
        qs[(c4 * 4 + 3) * 64 + qq] = f.w;
    }
    if (tid < 64) ksm[tid] = ksum[bh * 64 + tid];

    float vmax[8];
    #pragma unroll
    for (int i = 0; i < 8; ++i) vmax[i] = -INFINITY;

    for (int kt = 0; kt < 16; ++kt) {
        __syncthreads();
        #pragma unroll
        for (int s = 0; s < 8; ++s) {
            int u = tid + 256 * s;          // 0..2047
            int kk = u & 127, c4 = u >> 7;  // c4: 0..15
            float4 f = *(const float4*)&kb[(kt * 128 + kk) * HDIM + c4 * 4];
            ks[(c4 * 4 + 0) * 128 + kk] = f.x;
            ks[(c4 * 4 + 1) * 128 + kk] = f.y;
            ks[(c4 * 4 + 2) * 128 + kk] = f.z;
            ks[(c4 * 4 + 3) * 128 + kk] = f.w;
        }
        if (tid < 128) msk[tid] = (count[kt * 128 + tid] > 0) ? 0.0f : -INFINITY;
        __syncthreads();

        float dot[8][4];
        #pragma unroll
        for (int i = 0; i < 8; ++i)
            #pragma unroll
            for (int j = 0; j < 4; ++j) dot[i][j] = 0.0f;

        #pragma unroll 8
        for (int d = 0; d < 64; ++d) {
            float4 kv = *(const float4*)&ks[d * 128 + tj * 4];
            float4 qa = *(const float4*)&qs[d * 64 + ti * 8];
            float4 qb4 = *(const float4*)&qs[d * 64 + ti * 8 + 4];
            float qv[8] = {qa.x, qa.y, qa.z, qa.w, qb4.x, qb4.y, qb4.z, qb4.w};
            #pragma unroll
            for (int i = 0; i < 8; ++i) {
                dot[i][0] = fmaf(qv[i], kv.x, dot[i][0]);
                dot[i][1] = fmaf(qv[i], kv.y, dot[i][1]);
                dot[i][2] = fmaf(qv[i], kv.z, dot[i][2]);
                dot[i][3] = fmaf(qv[i], kv.w, dot[i][3]);
            }
        }
        #pragma unroll
        for (int j = 0; j < 4; ++j) {
            float mj = msk[tj * 4 + j];  // 0 or -inf
            #pragma unroll
            for (int i = 0; i < 8; ++i)
                vmax[i] = fmaxf(vmax[i], dot[i][j] + mj);
        }
    }
    __syncthreads();

    float* red = ks;
    #pragma unroll
    for (int i = 0; i < 8; ++i) red[(ti * 8 + i) * 33 + tj] = vmax[i];
    __syncthreads();
    if (tid < 64) {
        int qq = tid;
        float m = -INFINITY;
        #pragma unroll
        for (int j = 0; j < 32; ++j) m = fmaxf(m, red[qq * 33 + j]);
        float sdot = 0.f;
        #pragma unroll
        for (int d = 0; d < 64; ++d) sdot = fmaf(qs[d * 64 + qq], ksm[d], sdot);
        spars[bh * T_LEN + q0 + qq] = m - sdot * (1.0f / 2048.0f);
    }
}

// ---------------------------------------------------------------------------
// Kernel D: top-40 per bh by iterative argmax (ties -> smaller index).
// ---------------------------------------------------------------------------
__global__ __launch_bounds__(256)
void topk_kernel(const float* __restrict__ spars, int* __restrict__ topi)
{
    __shared__ float vals[T_LEN];
    __shared__ float rv[256];
    __shared__ int   ri[256];
    const int bh = blockIdx.x, tid = threadIdx.x;
    for (int j = tid; j < T_LEN; j += 256) vals[j] = spars[bh * T_LEN + j];
    __syncthreads();
    for (int it = 0; it < USEL; ++it) {
        float bv = -INFINITY; int bi = 0;
        #pragma unroll
        for (int jj = 0; jj < 8; ++jj) {
            int j = tid * 8 + jj;
            float vv = vals[j];
            if (vv > bv) { bv = vv; bi = j; }
        }
        rv[tid] = bv; ri[tid] = bi;
        __syncthreads();
        for (int s = 128; s > 0; s >>= 1) {
            if (tid < s) {
                float ov = rv[tid + s]; int oi = ri[tid + s];
                if (ov > rv[tid] || (ov == rv[tid] && oi < ri[tid])) { rv[tid] = ov; ri[tid] = oi; }
            }
            __syncthreads();
        }
        if (tid == 0) {
            int win = ri[0] & (T_LEN - 1);
            topi[bh * USEL + it] = win;
            vals[win] = -INFINITY;
        }
        __syncthreads();
    }
}

// ---------------------------------------------------------------------------
// Kernel E: softmax attention for the 40 selected queries per bh.
// ---------------------------------------------------------------------------
__global__ __launch_bounds__(256)
void sel_attn_kernel(const float* __restrict__ q, const float* __restrict__ k,
                     const float* __restrict__ v, const int* __restrict__ topi,
                     float* __restrict__ attn)
{
    alignas(16) __shared__ float qv[64];
    alignas(16) __shared__ float sc[T_LEN];
    __shared__ float red[256];
    __shared__ float part[256];

    const int u = blockIdx.x, bh = blockIdx.y, tid = threadIdx.x;
    const int tq = topi[bh * USEL + u] & (T_LEN - 1);
    if (tid < 64) qv[tid] = q[((size_t)bh * T_LEN + tq) * HDIM + tid];
    __syncthreads();

    const float* kb = k + (size_t)bh * T_LEN * HDIM;
    const float* vb = v + (size_t)bh * T_LEN * HDIM;

    float lmax = -INFINITY;
    #pragma unroll
    for (int s = 0; s < 8; ++s) {
        int t = tid + 256 * s;
        const float* kr = kb + t * HDIM;
        float acc = 0.f;
        #pragma unroll
        for (int d4 = 0; d4 < 16; ++d4) {
            float4 kf = *(const float4*)&kr[d4 * 4];
            float4 qf = *(const float4*)&qv[d4 * 4];
            acc = fmaf(kf.x, qf.x, acc);
            acc = fmaf(kf.y, qf.y, acc);
            acc = fmaf(kf.z, qf.z, acc);
            acc = fmaf(kf.w, qf.w, acc);
        }
        sc[t] = acc;
        lmax = fmaxf(lmax, acc);
    }
    red[tid] = lmax;
    __syncthreads();
    for (int s = 128; s > 0; s >>= 1) {
        if (tid < s) red[tid] = fmaxf(red[tid], red[tid + s]);
        __syncthreads();
    }
    float m = red[0];
    __syncthreads();

    float lsum = 0.f;
    #pragma unroll
    for (int s = 0; s < 8; ++s) {
        int t = tid + 256 * s;
        float p = __expf(sc[t] - m);
        sc[t] = p;
        lsum += p;
    }
    red[tid] = lsum;
    __syncthreads();
    for (int s = 128; s > 0; s >>= 1) {
        if (tid < s) red[tid] += red[tid + s];
        __syncthreads();
    }
    float l = red[0];

    const int w = tid >> 6, lane = tid & 63;
    float acc = 0.f;
    #pragma unroll 4
    for (int it = 0; it < 512; ++it) {
        int t = w * 512 + it;
        acc = fmaf(sc[t], vb[t * HDIM + lane], acc);
    }
    part[w * 64 + lane] = acc;
    __syncthreads();
    if (tid < 64) {
        float tot = part[tid] + part[64 + tid] + part[128 + tid] + part[192 + tid];
        attn[((size_t)bh * USEL + u) * HDIM + tid] = tot / l;
    }
}

// ---------------------------------------------------------------------------
// Kernel F1: fill context (B,T,E layout, fp32) with per-head vmean.
// ---------------------------------------------------------------------------
__global__ __launch_bounds__(256)
void ctx_fill_kernel(const float* __restrict__ vmean, float* __restrict__ ctx)
{
    int flat = blockIdx.x * 256 + threadIdx.x;
    int d = flat & 63, h = (flat >> 6) & 7, b = flat >> 20;
    int bh = (b << 3) | h;
    ctx[flat] = vmean[bh * 64 + d];
}

// ---------------------------------------------------------------------------
// Kernel F2: scatter attn rows into context at top_idx positions.
// ---------------------------------------------------------------------------
__global__ void ctx_scatter_kernel(const float* __restrict__ attn, const int* __restrict__ topi,
                                   float* __restrict__ ctx)
{
    const int u = blockIdx.x, bh = blockIdx.y, d = threadIdx.x;
    const int b = bh >> 3, h = bh & 7;
    const int t = topi[bh * USEL + u] & (T_LEN - 1);
    ctx[(size_t)(b * T_LEN + t) * EMB + h * 64 + d] =
        attn[((size_t)bh * USEL + u) * HDIM + d];
}

// ---------------------------------------------------------------------------
// Kernel G: out = ctx @ Wo^T + bo (fp32 VALU GEMM, same tiling as Kernel A).
// ---------------------------------------------------------------------------
__global__ __launch_bounds__(256)
void out_proj_kernel(const float* __restrict__ A, const float* __restrict__ Wo,
                     const float* __restrict__ bo, float* __restrict__ out)
{
    alignas(16) __shared__ float Xs[64 * 64];    // [k][m]
    alignas(16) __shared__ float Wt[64 * 128];   // [k][n]

    const int tid = threadIdx.x;
    const int m0 = blockIdx.x * 64;
    const int n0 = blockIdx.y * 128;
    const int ti = tid >> 5, tj = tid & 31;

    float acc[8][4];
    #pragma unroll
    for (int i = 0; i < 8; ++i)
        #pragma unroll
        for (int j = 0; j < 4; ++j) acc[i][j] = 0.0f;

    for (int kc = 0; kc < EMB; kc += 64) {
        __syncthreads();
        #pragma unroll
        for (int s = 0; s < 4; ++s) {
            int u = tid + 256 * s;
            int mm = u & 63, c4 = u >> 6;
            float4 f = *(const float4*)&A[(m0 + mm) * EMB + kc + c4 * 4];
            Xs[(c4 * 4 + 0) * 64 + mm] = f.x;
            Xs[(c4 * 4 + 1) * 64 + mm] = f.y;
            Xs[(c4 * 4 + 2) * 64 + mm] = f.z;
            Xs[(c4 * 4 + 3) * 64 + mm] = f.w;
        }
        #pragma unroll
        for (int s = 0; s < 8; ++s) {
            int u = tid + 256 * s;
            int nn = u & 127, c4 = u >> 7;
            float4 f = *(const float4*)&Wo[(n0 + nn) * EMB + kc + c4 * 4];
            Wt[(c4 * 4 + 0) * 128 + nn] = f.x;
            Wt[(c4 * 4 + 1) * 128 + nn] = f.y;
            Wt[(c4 * 4 + 2) * 128 + nn] = f.z;
            Wt[(c4 * 4 + 3) * 128 + nn] = f.w;
        }
        __syncthreads();

        #pragma unroll 8
        for (int k = 0; k < 64; ++k) {
            float4 wv = *(const float4*)&Wt[k * 128 + tj * 4];
            float4 xa = *(const float4*)&Xs[k * 64 + ti * 8];
            float4 xb = *(const float4*)&Xs[k * 64 + ti * 8 + 4];
            float xv[8] = {xa.x, xa.y, xa.z, xa.w, xb.x, xb.y, xb.z, xb.w};
            #pragma unroll
            for (int i = 0; i < 8; ++i) {
                acc[i][0] = fmaf(xv[i], wv.x, acc[i][0]);
                acc[i][1] = fmaf(xv[i], wv.y, acc[i][1]);
                acc[i][2] = fmaf(xv[i], wv.z, acc[i][2]);
                acc[i][3] = fmaf(xv[i], wv.w, acc[i][3]);
            }
        }
    }

    const int n = n0 + tj * 4;
    float4 bf4 = *(const float4*)&bo[n];
    #pragma unroll
    for (int i = 0; i < 8; ++i) {
        int m = m0 + ti * 8 + i;
        float4 v4;
        v4.x = acc[i][0] + bf4.x;
        v4.y = acc[i][1] + bf4.y;
        v4.z = acc[i][2] + bf4.z;
        v4.w = acc[i][3] + bf4.w;
        *(float4*)&out[(size_t)m * EMB + n] = v4;
    }
}

// ---------------------------------------------------------------------------
// Diagnostic: if ws_size is too small, report it via d_out (absmax ~= MiB).
// ---------------------------------------------------------------------------
__global__ __launch_bounds__(256)
void ws_diag_kernel(float* __restrict__ out, int n, float mib)
{
    int flat = blockIdx.x * 256 + threadIdx.x;
    if (flat < n) out[flat] = mib;
}

// ---------------------------------------------------------------------------
extern "C" void kernel_launch(void* const* d_in, const int* in_sizes, int n_in,
                              void* d_out, int out_size, void* d_ws, size_t ws_size,
                              hipStream_t stream)
{
    // fp32 inputs/outputs in dict order (confirmed round 5). Bind by size,
    // same-size tensors in encounter (=dict) order: Wq, Wk, Wv, Wo.
    const float* X = nullptr; const int* idxs = nullptr;
    const float* Wseen[4] = {nullptr, nullptr, nullptr, nullptr};
    const float* bseen[4] = {nullptr, nullptr, nullptr, nullptr};
    int nw = 0, nb = 0, u_part = 2048;
    for (int i = 0; i < n_in; ++i) {
        int sz = in_sizes[i];
        if (sz == EMB * EMB * 16) { if (!X) X = (const float*)d_in[i]; }
        else if (sz == T_LEN)     { if (!idxs) { idxs = (const int*)d_in[i]; u_part = sz; } }
        else if (sz == EMB * EMB) { if (nw < 4) Wseen[nw++] = (const float*)d_in[i]; }
        else if (sz == EMB)       { if (nb < 4) bseen[nb++] = (const float*)d_in[i]; }
    }
    if (!X || !idxs || nw < 4 || nb < 4) {
        X = (const float*)d_in[0]; idxs = (const int*)d_in[1];
        Wseen[0] = (const float*)d_in[2]; bseen[0] = (const float*)d_in[3];
        Wseen[1] = (const float*)d_in[4]; bseen[1] = (const float*)d_in[5];
        Wseen[2] = (const float*)d_in[6]; bseen[2] = (const float*)d_in[7];
        Wseen[3] = (const float*)d_in[8]; bseen[3] = (const float*)d_in[9];
        u_part = in_sizes[1];
    }
    const float *Wq = Wseen[0], *Wk = Wseen[1], *Wv = Wseen[2], *Wo = Wseen[3];
    const float *bq = bseen[0], *bk = bseen[1], *bv = bseen[2], *bo = bseen[3];

    // Workspace (peak 50,951,168 B, same as round 5):
    //   [0, 48MB):  qw / kw / vw (fp32; qw overlaid by ctx after sel_attn)
    //   tail at 48MB (floats): attn 81920 | spars 65536 | count 2048i |
    //                          ksum 2048 | vmean 2048 | topi 1280i
    //   kpart/vpart (16384+16384) OVERLAY attn region (disjoint liveness:
    //   parts die at reduce; attn/spars written later).
    const size_t NEED = 50951168ULL;
    if (ws_size < NEED) {
        ws_diag_kernel<<<(out_size + 255) / 256, 256, 0, stream>>>(
            (float*)d_out, out_size, (float)(ws_size >> 20));
        return;
    }

    float* ws    = (float*)d_ws;
    float* qw    = ws;                    // 32*2048*64 fp32
    float* kw    = qw + 4194304;
    float* vw    = kw + 4194304;
    float* tail  = vw + 4194304;          // 48MB mark
    float* attn  = tail;                  // 81920
    float* spars = tail + 81920;          // 65536
    int*   count = (int*)(tail + 147456); // 2048
    float* ksum  = tail + 149504;         // 2048
    float* vmean = tail + 151552;         // 2048
    int*   topi  = (int*)(tail + 153600); // 1280
    float* kpart = tail;                  // 16384 (overlay attn)
    float* vpart = tail + 16384;          // 16384 (still within attn's 81920)
    float* ctx   = (float*)d_ws;          // 8192*512 fp32, overlay on qw

    qkv_proj_kernel<<<dim3(128, 4, 3), 256, 0, stream>>>(X, Wq, bq, Wk, bk, Wv, bv, qw, kw, vw);
    count_kernel<<<1, 256, 0, stream>>>(idxs, u_part, count);
    ksum_vmean_part_kernel<<<dim3(8, 32), 256, 0, stream>>>(count, kw, vw, kpart, vpart);
    ksum_vmean_reduce_kernel<<<32, 64, 0, stream>>>(kpart, vpart, ksum, vmean);
    sparsity_scan_kernel<<<dim3(32, 32), 256, 0, stream>>>(qw, kw, ksum, count, spars);
    topk_kernel<<<32, 256, 0, stream>>>(spars, topi);
    sel_attn_kernel<<<dim3(USEL, BHEADS), 256, 0, stream>>>(qw, kw, vw, topi, attn);
    // qw dead from here; ctx takes over that memory.
    ctx_fill_kernel<<<16384, 256, 0, stream>>>(vmean, ctx);
    ctx_scatter_kernel<<<dim3(USEL, BHEADS), 64, 0, stream>>>(attn, topi, ctx);
    out_proj_kernel<<<dim3(128, 4), 256, 0, stream>>>(ctx, Wo, bo, (float*)d_out);
}

// Round 7
// 707.681 us; speedup vs baseline: 1.5925x; 1.1378x over previous
//
#include <hip/hip_runtime.h>
#include <hip/hip_bf16.h>
#include <math.h>

#define T_LEN 2048
#define EMB   512
#define NHEAD 8
#define HDIM  64
#define BHEADS 32
#define USEL  40

// ---------------------------------------------------------------------------
// Kernel A: fused QKV projection (fp32 VALU GEMM), 128x128 tile, 8x8/thread.
// Y = X @ W^T + b (q additionally *0.125), written per-head [bh][t][d].
// K-accumulation order (kc chunks of 64, d-sequential) identical to round 6
// -> q/k values bitwise stable -> top-k selection unchanged.
// ---------------------------------------------------------------------------
__global__ __launch_bounds__(256)
void qkv_proj_kernel(const float* __restrict__ X,
                     const float* __restrict__ Wq, const float* __restrict__ bq,
                     const float* __restrict__ Wk, const float* __restrict__ bk,
                     const float* __restrict__ Wv, const float* __restrict__ bv,
                     float* __restrict__ qo, float* __restrict__ ko, float* __restrict__ vo)
{
    alignas(16) __shared__ float Xs[64 * 128];   // [k][m]
    alignas(16) __shared__ float Wt[64 * 128];   // [k][n]

    const int z = blockIdx.z;
    const float* W; const float* bias; float* dst; float scale;
    if (z == 0)      { W = Wq; bias = bq; dst = qo; scale = 0.125f; }
    else if (z == 1) { W = Wk; bias = bk; dst = ko; scale = 1.0f;   }
    else             { W = Wv; bias = bv; dst = vo; scale = 1.0f;   }

    const int tid = threadIdx.x;
    const int m0 = blockIdx.x * 128;
    const int n0 = blockIdx.y * 128;
    const int ti = tid >> 4, tj = tid & 15;   // 16 m-groups x 16 n-groups

    float acc[8][8];
    #pragma unroll
    for (int i = 0; i < 8; ++i)
        #pragma unroll
        for (int j = 0; j < 8; ++j) acc[i][j] = 0.0f;

    for (int kc = 0; kc < EMB; kc += 64) {
        __syncthreads();
        #pragma unroll
        for (int s = 0; s < 8; ++s) {
            int u = tid + 256 * s;          // 0..2047
            int mm = u & 127, c4 = u >> 7;  // c4: 0..15
            float4 f = *(const float4*)&X[(m0 + mm) * EMB + kc + c4 * 4];
            Xs[(c4 * 4 + 0) * 128 + mm] = f.x;
            Xs[(c4 * 4 + 1) * 128 + mm] = f.y;
            Xs[(c4 * 4 + 2) * 128 + mm] = f.z;
            Xs[(c4 * 4 + 3) * 128 + mm] = f.w;
            float4 g = *(const float4*)&W[(n0 + mm) * EMB + kc + c4 * 4];
            Wt[(c4 * 4 + 0) * 128 + mm] = g.x;
            Wt[(c4 * 4 + 1) * 128 + mm] = g.y;
            Wt[(c4 * 4 + 2) * 128 + mm] = g.z;
            Wt[(c4 * 4 + 3) * 128 + mm] = g.w;
        }
        __syncthreads();

        #pragma unroll 4
        for (int k = 0; k < 64; ++k) {
            float4 xa = *(const float4*)&Xs[k * 128 + ti * 8];
            float4 xb = *(const float4*)&Xs[k * 128 + ti * 8 + 4];
            float4 wa = *(const float4*)&Wt[k * 128 + tj * 8];
            float4 wb = *(const float4*)&Wt[k * 128 + tj * 8 + 4];
            float xv[8] = {xa.x, xa.y, xa.z, xa.w, xb.x, xb.y, xb.z, xb.w};
            float wv[8] = {wa.x, wa.y, wa.z, wa.w, wb.x, wb.y, wb.z, wb.w};
            #pragma unroll
            for (int i = 0; i < 8; ++i)
                #pragma unroll
                for (int j = 0; j < 8; ++j)
                    acc[i][j] = fmaf(xv[i], wv[j], acc[i][j]);
        }
    }

    const int n = n0 + tj * 8;            // 8 cols within one head (n&63 <= 56)
    const int h = n >> 6, d = n & 63;
    float bf[8];
    #pragma unroll
    for (int j = 0; j < 8; ++j) bf[j] = bias[n + j];
    #pragma unroll
    for (int i = 0; i < 8; ++i) {
        int m = m0 + ti * 8 + i;
        int b = m >> 11, t = m & 2047;
        float* dp = &dst[((size_t)((b * NHEAD + h) * T_LEN + t)) * HDIM + d];
        float4 v0, v1;
        v0.x = (acc[i][0] + bf[0]) * scale; v0.y = (acc[i][1] + bf[1]) * scale;
        v0.z = (acc[i][2] + bf[2]) * scale; v0.w = (acc[i][3] + bf[3]) * scale;
        v1.x = (acc[i][4] + bf[4]) * scale; v1.y = (acc[i][5] + bf[5]) * scale;
        v1.z = (acc[i][6] + bf[6]) * scale; v1.w = (acc[i][7] + bf[7]) * scale;
        *(float4*)dp = v0;
        *(float4*)(dp + 4) = v1;
    }
}

// ---------------------------------------------------------------------------
// Kernel B1: count[t] = multiplicity of t in index_sample (LDS atomics, 1 blk).
// ---------------------------------------------------------------------------
__global__ __launch_bounds__(256)
void count_kernel(const int* __restrict__ idxs, int n, int* __restrict__ count)
{
    __shared__ int cnt[T_LEN];
    const int tid = threadIdx.x;
    for (int j = tid; j < T_LEN; j += 256) cnt[j] = 0;
    __syncthreads();
    for (int i = tid; i < n; i += 256) atomicAdd(&cnt[idxs[i] & (T_LEN - 1)], 1);
    __syncthreads();
    for (int j = tid; j < T_LEN; j += 256) count[j] = cnt[j];
}

// ---------------------------------------------------------------------------
// Kernel B1b: compact distinct sampled indices -> klist[0..nc), pad to the
// next multiple of 128 with klist[0] (duplicate keys don't change a max).
// ---------------------------------------------------------------------------
__global__ __launch_bounds__(256)
void compact_kernel(const int* __restrict__ count, int* __restrict__ klist,
                    int* __restrict__ ncp)
{
    __shared__ int th_tot[256];
    __shared__ int th_off[256];
    __shared__ int ncs;
    const int tid = threadIdx.x;
    const int base = tid * 8;
    int flags[8]; int loc = 0;
    #pragma unroll
    for (int j = 0; j < 8; ++j) { flags[j] = (count[base + j] > 0); loc += flags[j]; }
    th_tot[tid] = loc;
    __syncthreads();
    if (tid == 0) {
        int run = 0;
        for (int i = 0; i < 256; ++i) { th_off[i] = run; run += th_tot[i]; }
        ncs = run;
        ncp[0] = run;
    }
    __syncthreads();
    int off = th_off[tid];
    #pragma unroll
    for (int j = 0; j < 8; ++j)
        if (flags[j]) klist[off++] = base + j;
    __syncthreads();
    const int nc = ncs;
    const int nt = (nc + 127) & ~127;
    const int k0 = klist[0];
    for (int j = nc + tid; j < nt; j += 256) klist[j] = k0;
}

// ---------------------------------------------------------------------------
// Kernel B2a: partial ksum/vsum per (bh, slice of 256 t). Coalesced float4
// streaming: ksum = sum_t count[t]*k[t], vsum = sum_t v[t].
// ---------------------------------------------------------------------------
__global__ __launch_bounds__(256)
void ksum_vmean_part_kernel(const int* __restrict__ count,
                            const float* __restrict__ k, const float* __restrict__ v,
                            float* __restrict__ kpart, float* __restrict__ vpart)
{
    __shared__ int cs[256];
    alignas(16) __shared__ float rk[16 * 64];
    alignas(16) __shared__ float rv[16 * 64];

    const int sl = blockIdx.x, bh = blockIdx.y, tid = threadIdx.x;
    const int f4 = tid & 15, tg = tid >> 4;
    const int t0 = sl * 256;

    cs[tid] = count[t0 + tid];
    __syncthreads();

    const float4* k4 = (const float4*)(k + (size_t)bh * T_LEN * HDIM) + t0 * 16;
    const float4* v4 = (const float4*)(v + (size_t)bh * T_LEN * HDIM) + t0 * 16;

    float4 ak = {0.f, 0.f, 0.f, 0.f}, av = {0.f, 0.f, 0.f, 0.f};
    #pragma unroll
    for (int s = 0; s < 16; ++s) {
        int t = tg + s * 16;
        float c = (float)cs[t];
        float4 kf = k4[t * 16 + f4];
        float4 vf = v4[t * 16 + f4];
        ak.x = fmaf(c, kf.x, ak.x); ak.y = fmaf(c, kf.y, ak.y);
        ak.z = fmaf(c, kf.z, ak.z); ak.w = fmaf(c, kf.w, ak.w);
        av.x += vf.x; av.y += vf.y; av.z += vf.z; av.w += vf.w;
    }
    *(float4*)&rk[tg * 64 + f4 * 4] = ak;
    *(float4*)&rv[tg * 64 + f4 * 4] = av;
    __syncthreads();

    if (tid < 64) {
        float sk = 0.f, sv = 0.f;
        #pragma unroll
        for (int g = 0; g < 16; ++g) { sk += rk[g * 64 + tid]; sv += rv[g * 64 + tid]; }
        kpart[((size_t)bh * 8 + sl) * 64 + tid] = sk;
        vpart[((size_t)bh * 8 + sl) * 64 + tid] = sv;
    }
}

// ---------------------------------------------------------------------------
// Kernel B2b: reduce 8 slice-partials -> ksum[bh][d], vmean[bh][d].
// ---------------------------------------------------------------------------
__global__ __launch_bounds__(64)
void ksum_vmean_reduce_kernel(const float* __restrict__ kpart, const float* __restrict__ vpart,
                              float* __restrict__ ksum, float* __restrict__ vmean)
{
    const int bh = blockIdx.x, d = threadIdx.x;
    float sk = 0.f, sv = 0.f;
    #pragma unroll
    for (int sl = 0; sl < 8; ++sl) {
        sk += kpart[((size_t)bh * 8 + sl) * 64 + d];
        sv += vpart[((size_t)bh * 8 + sl) * 64 + d];
    }
    ksum[bh * 64 + d]  = sk;
    vmean[bh * 64 + d] = sv * (1.0f / 2048.0f);
}

// ---------------------------------------------------------------------------
// Kernel C: sparsity scan over COMPACTED sampled keys (fp32, 128q x 128k tile,
// 8x8 per-thread outer product). spars = max_{sampled}(q.k) - (q.ksum)/2048.
// Padding rows are duplicates of klist[0] -> no mask needed.
// ---------------------------------------------------------------------------
__global__ __launch_bounds__(256)
void sparsity_scan_kernel(const float* __restrict__ q, const float* __restrict__ k,
                          const float* __restrict__ ksum, const int* __restrict__ klist,
                          const int* __restrict__ ncp, float* __restrict__ spars)
{
    alignas(16) __shared__ float qs[64 * 128];   // [d][qq]
    alignas(16) __shared__ float ks[64 * 128];   // [d][kk] (reused as reduce buf)
    __shared__ float ksm[64];

    const int tid = threadIdx.x;
    const int bh = blockIdx.y;
    const int q0 = blockIdx.x * 128;
    const int ti = tid >> 4, tj = tid & 15;

    const float* qb = q + ((size_t)bh * T_LEN + q0) * HDIM;
    const float* kb = k + (size_t)bh * T_LEN * HDIM;
    const int ntiles = (ncp[0] + 127) >> 7;

    #pragma unroll
    for (int s = 0; s < 8; ++s) {
        int u = tid + 256 * s;          // 0..2047
        int qq = u & 127, c4 = u >> 7;  // c4: 0..15
        float4 f = *(const float4*)&qb[qq * HDIM + c4 * 4];
        qs[(c4 * 4 + 0) * 128 + qq] = f.x;
        qs[(c4 * 4 + 1) * 128 + qq] = f.y;
        qs[(c4 * 4 + 2) * 128 + qq] = f.z;
        qs[(c4 * 4 + 3) * 128 + qq] = f.w;
    }
    if (tid < 64) ksm[tid] = ksum[bh * 64 + tid];

    float vmax[8];
    #pragma unroll
    for (int i = 0; i < 8; ++i) vmax[i] = -INFINITY;

    for (int kt = 0; kt < ntiles; ++kt) {
        __syncthreads();   // previous tile's ks reads (and initial qs writes) done
        #pragma unroll
        for (int s = 0; s < 8; ++s) {
            int u = tid + 256 * s;
            int kk = u & 127, c4 = u >> 7;
            int row = klist[kt * 128 + kk];      // L2-hot gather index
            float4 f = *(const float4*)&kb[row * HDIM + c4 * 4];
            ks[(c4 * 4 + 0) * 128 + kk] = f.x;
            ks[(c4 * 4 + 1) * 128 + kk] = f.y;
            ks[(c4 * 4 + 2) * 128 + kk] = f.z;
            ks[(c4 * 4 + 3) * 128 + kk] = f.w;
        }
        __syncthreads();

        float dot[8][8];
        #pragma unroll
        for (int i = 0; i < 8; ++i)
            #pragma unroll
            for (int j = 0; j < 8; ++j) dot[i][j] = 0.0f;

        #pragma unroll 4
        for (int d = 0; d < 64; ++d) {
            float4 qa = *(const float4*)&qs[d * 128 + ti * 8];
            float4 qc = *(const float4*)&qs[d * 128 + ti * 8 + 4];
            float4 ka = *(const float4*)&ks[d * 128 + tj * 8];
            float4 kc = *(const float4*)&ks[d * 128 + tj * 8 + 4];
            float qv[8] = {qa.x, qa.y, qa.z, qa.w, qc.x, qc.y, qc.z, qc.w};
            float kv[8] = {ka.x, ka.y, ka.z, ka.w, kc.x, kc.y, kc.z, kc.w};
            #pragma unroll
            for (int i = 0; i < 8; ++i)
                #pragma unroll
                for (int j = 0; j < 8; ++j)
                    dot[i][j] = fmaf(qv[i], kv[j], dot[i][j]);
        }
        #pragma unroll
        for (int i = 0; i < 8; ++i) {
            float m8 = dot[i][0];
            #pragma unroll
            for (int j = 1; j < 8; ++j) m8 = fmaxf(m8, dot[i][j]);
            vmax[i] = fmaxf(vmax[i], m8);
        }
    }
    __syncthreads();

    float* red = ks;   // 128 rows x 17 stride = 2176 floats, fits in ks
    #pragma unroll
    for (int i = 0; i < 8; ++i) red[(ti * 8 + i) * 17 + tj] = vmax[i];
    __syncthreads();
    if (tid < 128) {
        float m = red[tid * 17];
        #pragma unroll
        for (int j = 1; j < 16; ++j) m = fmaxf(m, red[tid * 17 + j]);
        float sdot = 0.f;
        #pragma unroll
        for (int d = 0; d < 64; ++d) sdot = fmaf(qs[d * 128 + tid], ksm[d], sdot);
        spars[bh * T_LEN + q0 + tid] = m - sdot * (1.0f / 2048.0f);
    }
}

// ---------------------------------------------------------------------------
// Kernel D: top-40 per bh by iterative argmax (ties -> smaller index).
// ---------------------------------------------------------------------------
__global__ __launch_bounds__(256)
void topk_kernel(const float* __restrict__ spars, int* __restrict__ topi)
{
    __shared__ float vals[T_LEN];
    __shared__ float rv[256];
    __shared__ int   ri[256];
    const int bh = blockIdx.x, tid = threadIdx.x;
    for (int j = tid; j < T_LEN; j += 256) vals[j] = spars[bh * T_LEN + j];
    __syncthreads();
    for (int it = 0; it < USEL; ++it) {
        float bv = -INFINITY; int bi = 0;
        #pragma unroll
        for (int jj = 0; jj < 8; ++jj) {
            int j = tid * 8 + jj;
            float vv = vals[j];
            if (vv > bv) { bv = vv; bi = j; }
        }
        rv[tid] = bv; ri[tid] = bi;
        __syncthreads();
        for (int s = 128; s > 0; s >>= 1) {
            if (tid < s) {
                float ov = rv[tid + s]; int oi = ri[tid + s];
                if (ov > rv[tid] || (ov == rv[tid] && oi < ri[tid])) { rv[tid] = ov; ri[tid] = oi; }
            }
            __syncthreads();
        }
        if (tid == 0) {
            int win = ri[0] & (T_LEN - 1);
            topi[bh * USEL + it] = win;
            vals[win] = -INFINITY;
        }
        __syncthreads();
    }
}

// ---------------------------------------------------------------------------
// Kernel E: softmax attention for the 40 selected queries per bh.
// ---------------------------------------------------------------------------
__global__ __launch_bounds__(256)
void sel_attn_kernel(const float* __restrict__ q, const float* __restrict__ k,
                     const float* __restrict__ v, const int* __restrict__ topi,
                     float* __restrict__ attn)
{
    alignas(16) __shared__ float qv[64];
    alignas(16) __shared__ float sc[T_LEN];
    __shared__ float red[256];
    __shared__ float part[256];

    const int u = blockIdx.x, bh = blockIdx.y, tid = threadIdx.x;
    const int tq = topi[bh * USEL + u] & (T_LEN - 1);
    if (tid < 64) qv[tid] = q[((size_t)bh * T_LEN + tq) * HDIM + tid];
    __syncthreads();

    const float* kb = k + (size_t)bh * T_LEN * HDIM;
    const float* vb = v + (size_t)bh * T_LEN * HDIM;

    float lmax = -INFINITY;
    #pragma unroll
    for (int s = 0; s < 8; ++s) {
        int t = tid + 256 * s;
        const float* kr = kb + t * HDIM;
        float acc = 0.f;
        #pragma unroll
        for (int d4 = 0; d4 < 16; ++d4) {
            float4 kf = *(const float4*)&kr[d4 * 4];
            float4 qf = *(const float4*)&qv[d4 * 4];
            acc = fmaf(kf.x, qf.x, acc);
            acc = fmaf(kf.y, qf.y, acc);
            acc = fmaf(kf.z, qf.z, acc);
            acc = fmaf(kf.w, qf.w, acc);
        }
        sc[t] = acc;
        lmax = fmaxf(lmax, acc);
    }
    red[tid] = lmax;
    __syncthreads();
    for (int s = 128; s > 0; s >>= 1) {
        if (tid < s) red[tid] = fmaxf(red[tid], red[tid + s]);
        __syncthreads();
    }
    float m = red[0];
    __syncthreads();

    float lsum = 0.f;
    #pragma unroll
    for (int s = 0; s < 8; ++s) {
        int t = tid + 256 * s;
        float p = __expf(sc[t] - m);
        sc[t] = p;
        lsum += p;
    }
    red[tid] = lsum;
    __syncthreads();
    for (int s = 128; s > 0; s >>= 1) {
        if (tid < s) red[tid] += red[tid + s];
        __syncthreads();
    }
    float l = red[0];

    const int w = tid >> 6, lane = tid & 63;
    float acc = 0.f;
    #pragma unroll 4
    for (int it = 0; it < 512; ++it) {
        int t = w * 512 + it;
        acc = fmaf(sc[t], vb[t * HDIM + lane], acc);
    }
    part[w * 64 + lane] = acc;
    __syncthreads();
    if (tid < 64) {
        float tot = part[tid] + part[64 + tid] + part[128 + tid] + part[192 + tid];
        attn[((size_t)bh * USEL + u) * HDIM + tid] = tot / l;
    }
}

// ---------------------------------------------------------------------------
// Kernel F1: fill context (B,T,E layout, fp32) with per-head vmean.
// ---------------------------------------------------------------------------
__global__ __launch_bounds__(256)
void ctx_fill_kernel(const float* __restrict__ vmean, float* __restrict__ ctx)
{
    int flat = blockIdx.x * 256 + threadIdx.x;
    int d = flat & 63, h = (flat >> 6) & 7, b = flat >> 20;
    int bh = (b << 3) | h;
    ctx[flat] = vmean[bh * 64 + d];
}

// ---------------------------------------------------------------------------
// Kernel F2: scatter attn rows into context at top_idx positions.
// ---------------------------------------------------------------------------
__global__ void ctx_scatter_kernel(const float* __restrict__ attn, const int* __restrict__ topi,
                                   float* __restrict__ ctx)
{
    const int u = blockIdx.x, bh = blockIdx.y, d = threadIdx.x;
    const int b = bh >> 3, h = bh & 7;
    const int t = topi[bh * USEL + u] & (T_LEN - 1);
    ctx[(size_t)(b * T_LEN + t) * EMB + h * 64 + d] =
        attn[((size_t)bh * USEL + u) * HDIM + d];
}

// ---------------------------------------------------------------------------
// Kernel G: out = ctx @ Wo^T + bo (fp32 GEMM, 128x128 tile, 8x8/thread).
// ---------------------------------------------------------------------------
__global__ __launch_bounds__(256)
void out_proj_kernel(const float* __restrict__ A, const float* __restrict__ Wo,
                     const float* __restrict__ bo, float* __restrict__ out)
{
    alignas(16) __shared__ float Xs[64 * 128];   // [k][m]
    alignas(16) __shared__ float Wt[64 * 128];   // [k][n]

    const int tid = threadIdx.x;
    const int m0 = blockIdx.x * 128;
    const int n0 = blockIdx.y * 128;
    const int ti = tid >> 4, tj = tid & 15;

    float acc[8][8];
    #pragma unroll
    for (int i = 0; i < 8; ++i)
        #pragma unroll
        for (int j = 0; j < 8; ++j) acc[i][j] = 0.0f;

    for (int kc = 0; kc < EMB; kc += 64) {
        __syncthreads();
        #pragma unroll
        for (int s = 0; s < 8; ++s) {
            int u = tid + 256 * s;
            int mm = u & 127, c4 = u >> 7;
            float4 f = *(const float4*)&A[(m0 + mm) * EMB + kc + c4 * 4];
            Xs[(c4 * 4 + 0) * 128 + mm] = f.x;
            Xs[(c4 * 4 + 1) * 128 + mm] = f.y;
            Xs[(c4 * 4 + 2) * 128 + mm] = f.z;
            Xs[(c4 * 4 + 3) * 128 + mm] = f.w;
            float4 g = *(const float4*)&Wo[(n0 + mm) * EMB + kc + c4 * 4];
            Wt[(c4 * 4 + 0) * 128 + mm] = g.x;
            Wt[(c4 * 4 + 1) * 128 + mm] = g.y;
            Wt[(c4 * 4 + 2) * 128 + mm] = g.z;
            Wt[(c4 * 4 + 3) * 128 + mm] = g.w;
        }
        __syncthreads();

        #pragma unroll 4
        for (int k = 0; k < 64; ++k) {
            float4 xa = *(const float4*)&Xs[k * 128 + ti * 8];
            float4 xb = *(const float4*)&Xs[k * 128 + ti * 8 + 4];
            float4 wa = *(const float4*)&Wt[k * 128 + tj * 8];
            float4 wb = *(const float4*)&Wt[k * 128 + tj * 8 + 4];
            float xv[8] = {xa.x, xa.y, xa.z, xa.w, xb.x, xb.y, xb.z, xb.w};
            float wv[8] = {wa.x, wa.y, wa.z, wa.w, wb.x, wb.y, wb.z, wb.w};
            #pragma unroll
            for (int i = 0; i < 8; ++i)
                #pragma unroll
                for (int j = 0; j < 8; ++j)
                    acc[i][j] = fmaf(xv[i], wv[j], acc[i][j]);
        }
    }

    const int n = n0 + tj * 8;
    float bf[8];
    #pragma unroll
    for (int j = 0; j < 8; ++j) bf[j] = bo[n + j];
    #pragma unroll
    for (int i = 0; i < 8; ++i) {
        int m = m0 + ti * 8 + i;
        float* dp = &out[(size_t)m * EMB + n];
        float4 v0, v1;
        v0.x = acc[i][0] + bf[0]; v0.y = acc[i][1] + bf[1];
        v0.z = acc[i][2] + bf[2]; v0.w = acc[i][3] + bf[3];
        v1.x = acc[i][4] + bf[4]; v1.y = acc[i][5] + bf[5];
        v1.z = acc[i][6] + bf[6]; v1.w = acc[i][7] + bf[7];
        *(float4*)dp = v0;
        *(float4*)(dp + 4) = v1;
    }
}

// ---------------------------------------------------------------------------
// Diagnostic: if ws_size is too small, report it via d_out (absmax ~= MiB).
// ---------------------------------------------------------------------------
__global__ __launch_bounds__(256)
void ws_diag_kernel(float* __restrict__ out, int n, float mib)
{
    int flat = blockIdx.x * 256 + threadIdx.x;
    if (flat < n) out[flat] = mib;
}

// ---------------------------------------------------------------------------
extern "C" void kernel_launch(void* const* d_in, const int* in_sizes, int n_in,
                              void* d_out, int out_size, void* d_ws, size_t ws_size,
                              hipStream_t stream)
{
    // fp32 inputs/outputs in dict order (confirmed round 5/6). Bind by size,
    // same-size tensors in encounter (=dict) order: Wq, Wk, Wv, Wo.
    const float* X = nullptr; const int* idxs = nullptr;
    const float* Wseen[4] = {nullptr, nullptr, nullptr, nullptr};
    const float* bseen[4] = {nullptr, nullptr, nullptr, nullptr};
    int nw = 0, nb = 0, u_part = 2048;
    for (int i = 0; i < n_in; ++i) {
        int sz = in_sizes[i];
        if (sz == EMB * EMB * 16) { if (!X) X = (const float*)d_in[i]; }
        else if (sz == T_LEN)     { if (!idxs) { idxs = (const int*)d_in[i]; u_part = sz; } }
        else if (sz == EMB * EMB) { if (nw < 4) Wseen[nw++] = (const float*)d_in[i]; }
        else if (sz == EMB)       { if (nb < 4) bseen[nb++] = (const float*)d_in[i]; }
    }
    if (!X || !idxs || nw < 4 || nb < 4) {
        X = (const float*)d_in[0]; idxs = (const int*)d_in[1];
        Wseen[0] = (const float*)d_in[2]; bseen[0] = (const float*)d_in[3];
        Wseen[1] = (const float*)d_in[4]; bseen[1] = (const float*)d_in[5];
        Wseen[2] = (const float*)d_in[6]; bseen[2] = (const float*)d_in[7];
        Wseen[3] = (const float*)d_in[8]; bseen[3] = (const float*)d_in[9];
        u_part = in_sizes[1];
    }
    const float *Wq = Wseen[0], *Wk = Wseen[1], *Wv = Wseen[2], *Wo = Wseen[3];
    const float *bq = bseen[0], *bk = bseen[1], *bv = bseen[2], *bo = bseen[3];

    // Workspace (peak 50,951,168 B, unchanged):
    //   [0, 48MB):  qw / kw / vw (fp32; qw overlaid by ctx after sel_attn)
    //   tail at 48MB (floats): attn 81920 | spars 65536 | count 2048i |
    //                          ksum 2048 | vmean 2048 | topi 1280i
    //   OVERLAYS inside attn's 81920 (disjoint liveness vs attn):
    //     kpart [0,16384) | vpart [16384,32768) | klist [32768,34816)i | ncp [34816]i
    const size_t NEED = 50951168ULL;
    if (ws_size < NEED) {
        ws_diag_kernel<<<(out_size + 255) / 256, 256, 0, stream>>>(
            (float*)d_out, out_size, (float)(ws_size >> 20));
        return;
    }

    float* ws    = (float*)d_ws;
    float* qw    = ws;                    // 32*2048*64 fp32
    float* kw    = qw + 4194304;
    float* vw    = kw + 4194304;
    float* tail  = vw + 4194304;          // 48MB mark
    float* attn  = tail;                  // 81920
    float* spars = tail + 81920;          // 65536
    int*   count = (int*)(tail + 147456); // 2048
    float* ksum  = tail + 149504;         // 2048
    float* vmean = tail + 151552;         // 2048
    int*   topi  = (int*)(tail + 153600); // 1280
    float* kpart = tail;                  // overlay on attn
    float* vpart = tail + 16384;
    int*   klist = (int*)(tail + 32768);  // 2048 (padded compact list)
    int*   ncp   = (int*)(tail + 34816);  // 1
    float* ctx   = (float*)d_ws;          // 8192*512 fp32, overlay on qw

    qkv_proj_kernel<<<dim3(64, 4, 3), 256, 0, stream>>>(X, Wq, bq, Wk, bk, Wv, bv, qw, kw, vw);
    count_kernel<<<1, 256, 0, stream>>>(idxs, u_part, count);
    compact_kernel<<<1, 256, 0, stream>>>(count, klist, ncp);
    ksum_vmean_part_kernel<<<dim3(8, 32), 256, 0, stream>>>(count, kw, vw, kpart, vpart);
    ksum_vmean_reduce_kernel<<<32, 64, 0, stream>>>(kpart, vpart, ksum, vmean);
    sparsity_scan_kernel<<<dim3(16, 32), 256, 0, stream>>>(qw, kw, ksum, klist, ncp, spars);
    topk_kernel<<<32, 256, 0, stream>>>(spars, topi);
    sel_attn_kernel<<<dim3(USEL, BHEADS), 256, 0, stream>>>(qw, kw, vw, topi, attn);
    // qw dead from here; ctx takes over that memory.
    ctx_fill_kernel<<<16384, 256, 0, stream>>>(vmean, ctx);
    ctx_scatter_kernel<<<dim3(USEL, BHEADS), 64, 0, stream>>>(attn, topi, ctx);
    out_proj_kernel<<<dim3(64, 4), 256, 0, stream>>>(ctx, Wo, bo, (float*)d_out);
}

// Round 8
// 578.357 us; speedup vs baseline: 1.9486x; 1.2236x over previous
//
#include <hip/hip_runtime.h>
#include <hip/hip_bf16.h>
#include <math.h>

#define T_LEN 2048
#define EMB   512
#define NHEAD 8
#define HDIM  64
#define BHEADS 32
#define USEL  40

// ---------------------------------------------------------------------------
// Kernel A: fused QKV projection (fp32 VALU GEMM), 128x128 tile, 8x8/thread.
// Y = X @ W^T + b (q additionally *0.125), written per-head [bh][t][d].
// ---------------------------------------------------------------------------
__global__ __launch_bounds__(256)
void qkv_proj_kernel(const float* __restrict__ X,
                     const float* __restrict__ Wq, const float* __restrict__ bq,
                     const float* __restrict__ Wk, const float* __restrict__ bk,
                     const float* __restrict__ Wv, const float* __restrict__ bv,
                     float* __restrict__ qo, float* __restrict__ ko, float* __restrict__ vo)
{
    alignas(16) __shared__ float Xs[64 * 128];   // [k][m]
    alignas(16) __shared__ float Wt[64 * 128];   // [k][n]

    const int z = blockIdx.z;
    const float* W; const float* bias; float* dst; float scale;
    if (z == 0)      { W = Wq; bias = bq; dst = qo; scale = 0.125f; }
    else if (z == 1) { W = Wk; bias = bk; dst = ko; scale = 1.0f;   }
    else             { W = Wv; bias = bv; dst = vo; scale = 1.0f;   }

    const int tid = threadIdx.x;
    const int m0 = blockIdx.x * 128;
    const int n0 = blockIdx.y * 128;
    const int ti = tid >> 4, tj = tid & 15;

    float acc[8][8];
    #pragma unroll
    for (int i = 0; i < 8; ++i)
        #pragma unroll
        for (int j = 0; j < 8; ++j) acc[i][j] = 0.0f;

    for (int kc = 0; kc < EMB; kc += 64) {
        __syncthreads();
        #pragma unroll
        for (int s = 0; s < 8; ++s) {
            int u = tid + 256 * s;
            int mm = u & 127, c4 = u >> 7;
            float4 f = *(const float4*)&X[(m0 + mm) * EMB + kc + c4 * 4];
            Xs[(c4 * 4 + 0) * 128 + mm] = f.x;
            Xs[(c4 * 4 + 1) * 128 + mm] = f.y;
            Xs[(c4 * 4 + 2) * 128 + mm] = f.z;
            Xs[(c4 * 4 + 3) * 128 + mm] = f.w;
            float4 g = *(const float4*)&W[(n0 + mm) * EMB + kc + c4 * 4];
            Wt[(c4 * 4 + 0) * 128 + mm] = g.x;
            Wt[(c4 * 4 + 1) * 128 + mm] = g.y;
            Wt[(c4 * 4 + 2) * 128 + mm] = g.z;
            Wt[(c4 * 4 + 3) * 128 + mm] = g.w;
        }
        __syncthreads();

        #pragma unroll 4
        for (int k = 0; k < 64; ++k) {
            float4 xa = *(const float4*)&Xs[k * 128 + ti * 8];
            float4 xb = *(const float4*)&Xs[k * 128 + ti * 8 + 4];
            float4 wa = *(const float4*)&Wt[k * 128 + tj * 8];
            float4 wb = *(const float4*)&Wt[k * 128 + tj * 8 + 4];
            float xv[8] = {xa.x, xa.y, xa.z, xa.w, xb.x, xb.y, xb.z, xb.w};
            float wv[8] = {wa.x, wa.y, wa.z, wa.w, wb.x, wb.y, wb.z, wb.w};
            #pragma unroll
            for (int i = 0; i < 8; ++i)
                #pragma unroll
                for (int j = 0; j < 8; ++j)
                    acc[i][j] = fmaf(xv[i], wv[j], acc[i][j]);
        }
    }

    const int n = n0 + tj * 8;
    const int h = n >> 6, d = n & 63;
    float bf[8];
    #pragma unroll
    for (int j = 0; j < 8; ++j) bf[j] = bias[n + j];
    #pragma unroll
    for (int i = 0; i < 8; ++i) {
        int m = m0 + ti * 8 + i;
        int b = m >> 11, t = m & 2047;
        float* dp = &dst[((size_t)((b * NHEAD + h) * T_LEN + t)) * HDIM + d];
        float4 v0, v1;
        v0.x = (acc[i][0] + bf[0]) * scale; v0.y = (acc[i][1] + bf[1]) * scale;
        v0.z = (acc[i][2] + bf[2]) * scale; v0.w = (acc[i][3] + bf[3]) * scale;
        v1.x = (acc[i][4] + bf[4]) * scale; v1.y = (acc[i][5] + bf[5]) * scale;
        v1.z = (acc[i][6] + bf[6]) * scale; v1.w = (acc[i][7] + bf[7]) * scale;
        *(float4*)dp = v0;
        *(float4*)(dp + 4) = v1;
    }
}

// ---------------------------------------------------------------------------
// Kernel B1: count[t] = multiplicity of t in index_sample (LDS atomics, 1 blk).
// ---------------------------------------------------------------------------
__global__ __launch_bounds__(256)
void count_kernel(const int* __restrict__ idxs, int n, int* __restrict__ count)
{
    __shared__ int cnt[T_LEN];
    const int tid = threadIdx.x;
    for (int j = tid; j < T_LEN; j += 256) cnt[j] = 0;
    __syncthreads();
    for (int i = tid; i < n; i += 256) atomicAdd(&cnt[idxs[i] & (T_LEN - 1)], 1);
    __syncthreads();
    for (int j = tid; j < T_LEN; j += 256) count[j] = cnt[j];
}

// ---------------------------------------------------------------------------
// Kernel B1b: compact distinct sampled indices -> klist, pad to x128 with dup.
// ---------------------------------------------------------------------------
__global__ __launch_bounds__(256)
void compact_kernel(const int* __restrict__ count, int* __restrict__ klist,
                    int* __restrict__ ncp)
{
    __shared__ int th_tot[256];
    __shared__ int th_off[256];
    __shared__ int ncs;
    const int tid = threadIdx.x;
    const int base = tid * 8;
    int flags[8]; int loc = 0;
    #pragma unroll
    for (int j = 0; j < 8; ++j) { flags[j] = (count[base + j] > 0); loc += flags[j]; }
    th_tot[tid] = loc;
    __syncthreads();
    if (tid == 0) {
        int run = 0;
        for (int i = 0; i < 256; ++i) { th_off[i] = run; run += th_tot[i]; }
        ncs = run;
        ncp[0] = run;
    }
    __syncthreads();
    int off = th_off[tid];
    #pragma unroll
    for (int j = 0; j < 8; ++j)
        if (flags[j]) klist[off++] = base + j;
    __syncthreads();
    const int nc = ncs;
    const int nt = (nc + 127) & ~127;
    const int k0 = klist[0];
    for (int j = nc + tid; j < nt; j += 256) klist[j] = k0;
}

// ---------------------------------------------------------------------------
// Kernel B2a: partial ksum/vsum per (bh, slice). Coalesced float4 streaming.
// ---------------------------------------------------------------------------
__global__ __launch_bounds__(256)
void ksum_vmean_part_kernel(const int* __restrict__ count,
                            const float* __restrict__ k, const float* __restrict__ v,
                            float* __restrict__ kpart, float* __restrict__ vpart)
{
    __shared__ int cs[256];
    alignas(16) __shared__ float rk[16 * 64];
    alignas(16) __shared__ float rv[16 * 64];

    const int sl = blockIdx.x, bh = blockIdx.y, tid = threadIdx.x;
    const int f4 = tid & 15, tg = tid >> 4;
    const int t0 = sl * 256;

    cs[tid] = count[t0 + tid];
    __syncthreads();

    const float4* k4 = (const float4*)(k + (size_t)bh * T_LEN * HDIM) + t0 * 16;
    const float4* v4 = (const float4*)(v + (size_t)bh * T_LEN * HDIM) + t0 * 16;

    float4 ak = {0.f, 0.f, 0.f, 0.f}, av = {0.f, 0.f, 0.f, 0.f};
    #pragma unroll
    for (int s = 0; s < 16; ++s) {
        int t = tg + s * 16;
        float c = (float)cs[t];
        float4 kf = k4[t * 16 + f4];
        float4 vf = v4[t * 16 + f4];
        ak.x = fmaf(c, kf.x, ak.x); ak.y = fmaf(c, kf.y, ak.y);
        ak.z = fmaf(c, kf.z, ak.z); ak.w = fmaf(c, kf.w, ak.w);
        av.x += vf.x; av.y += vf.y; av.z += vf.z; av.w += vf.w;
    }
    *(float4*)&rk[tg * 64 + f4 * 4] = ak;
    *(float4*)&rv[tg * 64 + f4 * 4] = av;
    __syncthreads();

    if (tid < 64) {
        float sk = 0.f, sv = 0.f;
        #pragma unroll
        for (int g = 0; g < 16; ++g) { sk += rk[g * 64 + tid]; sv += rv[g * 64 + tid]; }
        kpart[((size_t)bh * 8 + sl) * 64 + tid] = sk;
        vpart[((size_t)bh * 8 + sl) * 64 + tid] = sv;
    }
}

// ---------------------------------------------------------------------------
// Kernel B2b: reduce 8 slice-partials -> ksum[bh][d], vmean[bh][d].
// ---------------------------------------------------------------------------
__global__ __launch_bounds__(64)
void ksum_vmean_reduce_kernel(const float* __restrict__ kpart, const float* __restrict__ vpart,
                              float* __restrict__ ksum, float* __restrict__ vmean)
{
    const int bh = blockIdx.x, d = threadIdx.x;
    float sk = 0.f, sv = 0.f;
    #pragma unroll
    for (int sl = 0; sl < 8; ++sl) {
        sk += kpart[((size_t)bh * 8 + sl) * 64 + d];
        sv += vpart[((size_t)bh * 8 + sl) * 64 + d];
    }
    ksum[bh * 64 + d]  = sk;
    vmean[bh * 64 + d] = sv * (1.0f / 2048.0f);
}

// ---------------------------------------------------------------------------
// Kernel C: sparsity scan over compacted sampled keys (fp32, 128x128 tile).
// ---------------------------------------------------------------------------
__global__ __launch_bounds__(256)
void sparsity_scan_kernel(const float* __restrict__ q, const float* __restrict__ k,
                          const float* __restrict__ ksum, const int* __restrict__ klist,
                          const int* __restrict__ ncp, float* __restrict__ spars)
{
    alignas(16) __shared__ float qs[64 * 128];   // [d][qq]
    alignas(16) __shared__ float ks[64 * 128];   // [d][kk] (reused as reduce buf)
    __shared__ float ksm[64];

    const int tid = threadIdx.x;
    const int bh = blockIdx.y;
    const int q0 = blockIdx.x * 128;
    const int ti = tid >> 4, tj = tid & 15;

    const float* qb = q + ((size_t)bh * T_LEN + q0) * HDIM;
    const float* kb = k + (size_t)bh * T_LEN * HDIM;
    const int ntiles = (ncp[0] + 127) >> 7;

    #pragma unroll
    for (int s = 0; s < 8; ++s) {
        int u = tid + 256 * s;
        int qq = u & 127, c4 = u >> 7;
        float4 f = *(const float4*)&qb[qq * HDIM + c4 * 4];
        qs[(c4 * 4 + 0) * 128 + qq] = f.x;
        qs[(c4 * 4 + 1) * 128 + qq] = f.y;
        qs[(c4 * 4 + 2) * 128 + qq] = f.z;
        qs[(c4 * 4 + 3) * 128 + qq] = f.w;
    }
    if (tid < 64) ksm[tid] = ksum[bh * 64 + tid];

    float vmax[8];
    #pragma unroll
    for (int i = 0; i < 8; ++i) vmax[i] = -INFINITY;

    for (int kt = 0; kt < ntiles; ++kt) {
        __syncthreads();
        #pragma unroll
        for (int s = 0; s < 8; ++s) {
            int u = tid + 256 * s;
            int kk = u & 127, c4 = u >> 7;
            int row = klist[kt * 128 + kk];
            float4 f = *(const float4*)&kb[row * HDIM + c4 * 4];
            ks[(c4 * 4 + 0) * 128 + kk] = f.x;
            ks[(c4 * 4 + 1) * 128 + kk] = f.y;
            ks[(c4 * 4 + 2) * 128 + kk] = f.z;
            ks[(c4 * 4 + 3) * 128 + kk] = f.w;
        }
        __syncthreads();

        float dot[8][8];
        #pragma unroll
        for (int i = 0; i < 8; ++i)
            #pragma unroll
            for (int j = 0; j < 8; ++j) dot[i][j] = 0.0f;

        #pragma unroll 4
        for (int d = 0; d < 64; ++d) {
            float4 qa = *(const float4*)&qs[d * 128 + ti * 8];
            float4 qc = *(const float4*)&qs[d * 128 + ti * 8 + 4];
            float4 ka = *(const float4*)&ks[d * 128 + tj * 8];
            float4 kc = *(const float4*)&ks[d * 128 + tj * 8 + 4];
            float qv[8] = {qa.x, qa.y, qa.z, qa.w, qc.x, qc.y, qc.z, qc.w};
            float kv[8] = {ka.x, ka.y, ka.z, ka.w, kc.x, kc.y, kc.z, kc.w};
            #pragma unroll
            for (int i = 0; i < 8; ++i)
                #pragma unroll
                for (int j = 0; j < 8; ++j)
                    dot[i][j] = fmaf(qv[i], kv[j], dot[i][j]);
        }
        #pragma unroll
        for (int i = 0; i < 8; ++i) {
            float m8 = dot[i][0];
            #pragma unroll
            for (int j = 1; j < 8; ++j) m8 = fmaxf(m8, dot[i][j]);
            vmax[i] = fmaxf(vmax[i], m8);
        }
    }
    __syncthreads();

    float* red = ks;
    #pragma unroll
    for (int i = 0; i < 8; ++i) red[(ti * 8 + i) * 17 + tj] = vmax[i];
    __syncthreads();
    if (tid < 128) {
        float m = red[tid * 17];
        #pragma unroll
        for (int j = 1; j < 16; ++j) m = fmaxf(m, red[tid * 17 + j]);
        float sdot = 0.f;
        #pragma unroll
        for (int d = 0; d < 64; ++d) sdot = fmaf(qs[d * 128 + tid], ksm[d], sdot);
        spars[bh * T_LEN + q0 + tid] = m - sdot * (1.0f / 2048.0f);
    }
}

// ---------------------------------------------------------------------------
// Kernel D: top-40 per bh by iterative argmax (ties -> smaller index).
// ---------------------------------------------------------------------------
__global__ __launch_bounds__(256)
void topk_kernel(const float* __restrict__ spars, int* __restrict__ topi)
{
    __shared__ float vals[T_LEN];
    __shared__ float rv[256];
    __shared__ int   ri[256];
    const int bh = blockIdx.x, tid = threadIdx.x;
    for (int j = tid; j < T_LEN; j += 256) vals[j] = spars[bh * T_LEN + j];
    __syncthreads();
    for (int it = 0; it < USEL; ++it) {
        float bv = -INFINITY; int bi = 0;
        #pragma unroll
        for (int jj = 0; jj < 8; ++jj) {
            int j = tid * 8 + jj;
            float vv = vals[j];
            if (vv > bv) { bv = vv; bi = j; }
        }
        rv[tid] = bv; ri[tid] = bi;
        __syncthreads();
        for (int s = 128; s > 0; s >>= 1) {
            if (tid < s) {
                float ov = rv[tid + s]; int oi = ri[tid + s];
                if (ov > rv[tid] || (ov == rv[tid] && oi < ri[tid])) { rv[tid] = ov; ri[tid] = oi; }
            }
            __syncthreads();
        }
        if (tid == 0) {
            int win = ri[0] & (T_LEN - 1);
            topi[bh * USEL + it] = win;
            vals[win] = -INFINITY;
        }
        __syncthreads();
    }
}

// ---------------------------------------------------------------------------
// Kernel E1: gather selected q rows -> qsel[bh][u][d]. (q dead afterwards)
// ---------------------------------------------------------------------------
__global__ __launch_bounds__(256)
void gather_q_kernel(const float* __restrict__ q, const int* __restrict__ topi,
                     float* __restrict__ qsel)
{
    const int bh = blockIdx.x, tid = threadIdx.x;
    for (int i = tid; i < USEL * HDIM; i += 256) {
        int u = i >> 6, d = i & 63;
        int t = topi[bh * USEL + u] & (T_LEN - 1);
        qsel[(size_t)bh * USEL * HDIM + i] = q[((size_t)bh * T_LEN + t) * HDIM + d];
    }
}

// ---------------------------------------------------------------------------
// Kernel E2: S[bh][u][t] = qsel[bh][u] . k[bh][t]. Grid (8 t-slices, 32 bh).
// K staged transposed [d][t] stride 257 (conflict-free), 5q x 8k per thread.
// K is read exactly once across the whole dispatch (16.8 MB).
// ---------------------------------------------------------------------------
__global__ __launch_bounds__(256)
void sel_scores_kernel(const float* __restrict__ qsel, const float* __restrict__ k,
                       float* __restrict__ S)
{
    __shared__ float qsT[64 * 41];    // [d][u] stride 41
    __shared__ float ksT[64 * 257];   // [d][t] stride 257

    const int sl = blockIdx.x, bh = blockIdx.y, tid = threadIdx.x;
    const int t0 = sl * 256;

    for (int i = tid; i < USEL * HDIM; i += 256) {
        int u = i >> 6, d = i & 63;
        qsT[d * 41 + u] = qsel[(size_t)bh * USEL * HDIM + i];
    }
    const float4* k4 = (const float4*)(k + (size_t)bh * T_LEN * HDIM);
    #pragma unroll
    for (int s = 0; s < 16; ++s) {
        int u = tid + 256 * s;          // 0..4095
        int c4 = u & 15, t = u >> 4;    // t 0..255
        float4 f = k4[(t0 + t) * 16 + c4];
        ksT[(c4 * 4 + 0) * 257 + t] = f.x;
        ksT[(c4 * 4 + 1) * 257 + t] = f.y;
        ksT[(c4 * 4 + 2) * 257 + t] = f.z;
        ksT[(c4 * 4 + 3) * 257 + t] = f.w;
    }
    __syncthreads();

    const int qg = tid >> 5;   // 0..7 -> 5 queries each
    const int kg = tid & 31;   // strided keys: kg + 32*j

    float acc[5][8];
    #pragma unroll
    for (int i = 0; i < 5; ++i)
        #pragma unroll
        for (int j = 0; j < 8; ++j) acc[i][j] = 0.0f;

    #pragma unroll 4
    for (int d = 0; d < 64; ++d) {
        float qv[5], kv[8];
        #pragma unroll
        for (int i = 0; i < 5; ++i) qv[i] = qsT[d * 41 + qg * 5 + i];
        #pragma unroll
        for (int j = 0; j < 8; ++j) kv[j] = ksT[d * 257 + kg + 32 * j];
        #pragma unroll
        for (int i = 0; i < 5; ++i)
            #pragma unroll
            for (int j = 0; j < 8; ++j)
                acc[i][j] = fmaf(qv[i], kv[j], acc[i][j]);
    }

    #pragma unroll
    for (int i = 0; i < 5; ++i) {
        float* sp = &S[((size_t)bh * USEL + qg * 5 + i) * T_LEN + t0 + kg];
        #pragma unroll
        for (int j = 0; j < 8; ++j) sp[32 * j] = acc[i][j];
    }
}

// ---------------------------------------------------------------------------
// Kernel E3: in-place softmax over each S row (1280 rows of 2048).
// ---------------------------------------------------------------------------
__global__ __launch_bounds__(256)
void sel_softmax_kernel(float* __restrict__ S)
{
    __shared__ float red[256];
    const int row = blockIdx.x, tid = threadIdx.x;
    float* sr = S + (size_t)row * T_LEN;

    float x[8];
    float m = -INFINITY;
    #pragma unroll
    for (int s = 0; s < 8; ++s) { x[s] = sr[tid + 256 * s]; m = fmaxf(m, x[s]); }
    red[tid] = m;
    __syncthreads();
    for (int s = 128; s > 0; s >>= 1) {
        if (tid < s) red[tid] = fmaxf(red[tid], red[tid + s]);
        __syncthreads();
    }
    m = red[0];
    __syncthreads();

    float sum = 0.f;
    #pragma unroll
    for (int s = 0; s < 8; ++s) { x[s] = __expf(x[s] - m); sum += x[s]; }
    red[tid] = sum;
    __syncthreads();
    for (int s = 128; s > 0; s >>= 1) {
        if (tid < s) red[tid] += red[tid + s];
        __syncthreads();
    }
    float inv = 1.0f / red[0];
    #pragma unroll
    for (int s = 0; s < 8; ++s) sr[tid + 256 * s] = x[s] * inv;
}

// ---------------------------------------------------------------------------
// Kernel E4: PV partial. Grid (16 t-slices, 32 bh). Each block: P[40][128] x
// V[128][64] -> partial O[40][64]. V read exactly once across dispatch.
// Thread: (qg 0..7 ->5q) x (dg 0..15 ->4d) x (th 0..1 t-half), LDS-combined.
// ---------------------------------------------------------------------------
__global__ __launch_bounds__(256)
void pv_part_kernel(const float* __restrict__ S, const float* __restrict__ v,
                    float* __restrict__ part)
{
    __shared__ float ps[USEL * 128];      // [q][t]
    __shared__ float vs[128 * 69];        // [t][d] stride 69
    __shared__ float obuf[128 * 20];

    const int sl = blockIdx.x, bh = blockIdx.y, tid = threadIdx.x;
    const int t0 = sl * 128;

    for (int i = tid; i < USEL * 128; i += 256) {
        int q = i >> 7, t = i & 127;
        ps[q * 128 + t] = S[((size_t)bh * USEL + q) * T_LEN + t0 + t];
    }
    const float4* v4 = (const float4*)(v + (size_t)bh * T_LEN * HDIM);
    #pragma unroll
    for (int s = 0; s < 8; ++s) {
        int u = tid + 256 * s;          // 0..2047
        int c4 = u & 15, t = u >> 4;    // t 0..127
        float4 f = v4[(t0 + t) * 16 + c4];
        vs[t * 69 + c4 * 4 + 0] = f.x;
        vs[t * 69 + c4 * 4 + 1] = f.y;
        vs[t * 69 + c4 * 4 + 2] = f.z;
        vs[t * 69 + c4 * 4 + 3] = f.w;
    }
    __syncthreads();

    const int qg = tid >> 5, r = tid & 31;
    const int dg = r >> 1, th = r & 1;
    const int tb = th * 64;

    float o[5][4];
    #pragma unroll
    for (int i = 0; i < 5; ++i)
        #pragma unroll
        for (int j = 0; j < 4; ++j) o[i][j] = 0.0f;

    #pragma unroll 4
    for (int tt = 0; tt < 64; ++tt) {
        int t = tb + tt;
        float pv[5];
        #pragma unroll
        for (int i = 0; i < 5; ++i) pv[i] = ps[(qg * 5 + i) * 128 + t];
        float4 vv = *(const float4*)&vs[t * 69 + dg * 4];
        #pragma unroll
        for (int i = 0; i < 5; ++i) {
            o[i][0] = fmaf(pv[i], vv.x, o[i][0]);
            o[i][1] = fmaf(pv[i], vv.y, o[i][1]);
            o[i][2] = fmaf(pv[i], vv.z, o[i][2]);
            o[i][3] = fmaf(pv[i], vv.w, o[i][3]);
        }
    }

    const int p = qg * 16 + dg;   // 0..127
    if (th == 1) {
        #pragma unroll
        for (int i = 0; i < 5; ++i)
            #pragma unroll
            for (int j = 0; j < 4; ++j) obuf[p * 20 + i * 4 + j] = o[i][j];
    }
    __syncthreads();
    if (th == 0) {
        float* pb = part + ((size_t)bh * 16 + sl) * (USEL * HDIM);
        #pragma unroll
        for (int i = 0; i < 5; ++i)
            #pragma unroll
            for (int j = 0; j < 4; ++j)
                pb[(qg * 5 + i) * HDIM + dg * 4 + j] = o[i][j] + obuf[p * 20 + i * 4 + j];
    }
}

// ---------------------------------------------------------------------------
// Kernel E5: deterministic merge of 16 PV partials -> attn[bh][u][d].
// ---------------------------------------------------------------------------
__global__ __launch_bounds__(256)
void pv_merge_kernel(const float* __restrict__ part, float* __restrict__ attn)
{
    const int bh = blockIdx.x, tid = threadIdx.x;
    for (int i = tid; i < USEL * HDIM; i += 256) {
        float s = 0.f;
        #pragma unroll
        for (int sl = 0; sl < 16; ++sl)
            s += part[((size_t)bh * 16 + sl) * (USEL * HDIM) + i];
        attn[(size_t)bh * USEL * HDIM + i] = s;
    }
}

// ---------------------------------------------------------------------------
// Kernel F1: fill context (B,T,E layout, fp32) with per-head vmean.
// ---------------------------------------------------------------------------
__global__ __launch_bounds__(256)
void ctx_fill_kernel(const float* __restrict__ vmean, float* __restrict__ ctx)
{
    int flat = blockIdx.x * 256 + threadIdx.x;
    int d = flat & 63, h = (flat >> 6) & 7, b = flat >> 20;
    int bh = (b << 3) | h;
    ctx[flat] = vmean[bh * 64 + d];
}

// ---------------------------------------------------------------------------
// Kernel F2: scatter attn rows into context at top_idx positions.
// ---------------------------------------------------------------------------
__global__ void ctx_scatter_kernel(const float* __restrict__ attn, const int* __restrict__ topi,
                                   float* __restrict__ ctx)
{
    const int u = blockIdx.x, bh = blockIdx.y, d = threadIdx.x;
    const int b = bh >> 3, h = bh & 7;
    const int t = topi[bh * USEL + u] & (T_LEN - 1);
    ctx[(size_t)(b * T_LEN + t) * EMB + h * 64 + d] =
        attn[((size_t)bh * USEL + u) * HDIM + d];
}

// ---------------------------------------------------------------------------
// Kernel G: out = ctx @ Wo^T + bo (fp32 GEMM, 128x128 tile, 8x8/thread).
// ---------------------------------------------------------------------------
__global__ __launch_bounds__(256)
void out_proj_kernel(const float* __restrict__ A, const float* __restrict__ Wo,
                     const float* __restrict__ bo, float* __restrict__ out)
{
    alignas(16) __shared__ float Xs[64 * 128];
    alignas(16) __shared__ float Wt[64 * 128];

    const int tid = threadIdx.x;
    const int m0 = blockIdx.x * 128;
    const int n0 = blockIdx.y * 128;
    const int ti = tid >> 4, tj = tid & 15;

    float acc[8][8];
    #pragma unroll
    for (int i = 0; i < 8; ++i)
        #pragma unroll
        for (int j = 0; j < 8; ++j) acc[i][j] = 0.0f;

    for (int kc = 0; kc < EMB; kc += 64) {
        __syncthreads();
        #pragma unroll
        for (int s = 0; s < 8; ++s) {
            int u = tid + 256 * s;
            int mm = u & 127, c4 = u >> 7;
            float4 f = *(const float4*)&A[(m0 + mm) * EMB + kc + c4 * 4];
            Xs[(c4 * 4 + 0) * 128 + mm] = f.x;
            Xs[(c4 * 4 + 1) * 128 + mm] = f.y;
            Xs[(c4 * 4 + 2) * 128 + mm] = f.z;
            Xs[(c4 * 4 + 3) * 128 + mm] = f.w;
            float4 g = *(const float4*)&Wo[(n0 + mm) * EMB + kc + c4 * 4];
            Wt[(c4 * 4 + 0) * 128 + mm] = g.x;
            Wt[(c4 * 4 + 1) * 128 + mm] = g.y;
            Wt[(c4 * 4 + 2) * 128 + mm] = g.z;
            Wt[(c4 * 4 + 3) * 128 + mm] = g.w;
        }
        __syncthreads();

        #pragma unroll 4
        for (int k = 0; k < 64; ++k) {
            float4 xa = *(const float4*)&Xs[k * 128 + ti * 8];
            float4 xb = *(const float4*)&Xs[k * 128 + ti * 8 + 4];
            float4 wa = *(const float4*)&Wt[k * 128 + tj * 8];
            float4 wb = *(const float4*)&Wt[k * 128 + tj * 8 + 4];
            float xv[8] = {xa.x, xa.y, xa.z, xa.w, xb.x, xb.y, xb.z, xb.w};
            float wv[8] = {wa.x, wa.y, wa.z, wa.w, wb.x, wb.y, wb.z, wb.w};
            #pragma unroll
            for (int i = 0; i < 8; ++i)
                #pragma unroll
                for (int j = 0; j < 8; ++j)
                    acc[i][j] = fmaf(xv[i], wv[j], acc[i][j]);
        }
    }

    const int n = n0 + tj * 8;
    float bf[8];
    #pragma unroll
    for (int j = 0; j < 8; ++j) bf[j] = bo[n + j];
    #pragma unroll
    for (int i = 0; i < 8; ++i) {
        int m = m0 + ti * 8 + i;
        float* dp = &out[(size_t)m * EMB + n];
        float4 v0, v1;
        v0.x = acc[i][0] + bf[0]; v0.y = acc[i][1] + bf[1];
        v0.z = acc[i][2] + bf[2]; v0.w = acc[i][3] + bf[3];
        v1.x = acc[i][4] + bf[4]; v1.y = acc[i][5] + bf[5];
        v1.z = acc[i][6] + bf[6]; v1.w = acc[i][7] + bf[7];
        *(float4*)dp = v0;
        *(float4*)(dp + 4) = v1;
    }
}

// ---------------------------------------------------------------------------
// Diagnostic: if ws_size is too small, report it via d_out (absmax ~= MiB).
// ---------------------------------------------------------------------------
__global__ __launch_bounds__(256)
void ws_diag_kernel(float* __restrict__ out, int n, float mib)
{
    int flat = blockIdx.x * 256 + threadIdx.x;
    if (flat < n) out[flat] = mib;
}

// ---------------------------------------------------------------------------
extern "C" void kernel_launch(void* const* d_in, const int* in_sizes, int n_in,
                              void* d_out, int out_size, void* d_ws, size_t ws_size,
                              hipStream_t stream)
{
    // fp32 inputs/outputs in dict order (confirmed). Bind by size; same-size
    // tensors in encounter (=dict) order: Wq, Wk, Wv, Wo.
    const float* X = nullptr; const int* idxs = nullptr;
    const float* Wseen[4] = {nullptr, nullptr, nullptr, nullptr};
    const float* bseen[4] = {nullptr, nullptr, nullptr, nullptr};
    int nw = 0, nb = 0, u_part = 2048;
    for (int i = 0; i < n_in; ++i) {
        int sz = in_sizes[i];
        if (sz == EMB * EMB * 16) { if (!X) X = (const float*)d_in[i]; }
        else if (sz == T_LEN)     { if (!idxs) { idxs = (const int*)d_in[i]; u_part = sz; } }
        else if (sz == EMB * EMB) { if (nw < 4) Wseen[nw++] = (const float*)d_in[i]; }
        else if (sz == EMB)       { if (nb < 4) bseen[nb++] = (const float*)d_in[i]; }
    }
    if (!X || !idxs || nw < 4 || nb < 4) {
        X = (const float*)d_in[0]; idxs = (const int*)d_in[1];
        Wseen[0] = (const float*)d_in[2]; bseen[0] = (const float*)d_in[3];
        Wseen[1] = (const float*)d_in[4]; bseen[1] = (const float*)d_in[5];
        Wseen[2] = (const float*)d_in[6]; bseen[2] = (const float*)d_in[7];
        Wseen[3] = (const float*)d_in[8]; bseen[3] = (const float*)d_in[9];
        u_part = in_sizes[1];
    }
    const float *Wq = Wseen[0], *Wk = Wseen[1], *Wv = Wseen[2], *Wo = Wseen[3];
    const float *bq = bseen[0], *bk = bseen[1], *bv = bseen[2], *bo = bseen[3];

    // Workspace (peak 50,951,168 B, unchanged):
    //   [0, 16MB):  qw (q; DEAD after gather_q) -> then S (10.5MB) + pvpart
    //               (5.2MB) -> then ctx (16MB, after pv_merge)
    //   [16,32MB):  kw   [32,48MB): vw
    //   tail at 48MB (floats): slotA 81920 (qsel then attn) | spars 65536 |
    //     count 2048i | ksum 2048 | vmean 2048 | topi 1280i
    //   overlays in slotA while attn not yet live: kpart/vpart/klist/ncp
    const size_t NEED = 50951168ULL;
    if (ws_size < NEED) {
        ws_diag_kernel<<<(out_size + 255) / 256, 256, 0, stream>>>(
            (float*)d_out, out_size, (float)(ws_size >> 20));
        return;
    }

    float* ws    = (float*)d_ws;
    float* qw    = ws;                    // 4,194,304 floats
    float* kw    = qw + 4194304;
    float* vw    = kw + 4194304;
    float* tail  = vw + 4194304;
    float* slotA = tail;                  // 81920: qsel, later attn
    float* spars = tail + 81920;          // 65536
    int*   count = (int*)(tail + 147456); // 2048
    float* ksum  = tail + 149504;         // 2048
    float* vmean = tail + 151552;         // 2048
    int*   topi  = (int*)(tail + 153600); // 1280
    float* kpart = tail;                  // overlay (dead before qsel written? no:
    float* vpart = tail + 16384;          //  kpart/vpart die at reduce, before gather)
    int*   klist = (int*)(tail + 32768);
    int*   ncp   = (int*)(tail + 34816);
    float* S     = qw;                    // 2,621,440 floats (q dead after gather)
    float* pvp   = qw + 2621440;          // 1,310,720 floats
    float* qsel  = slotA;
    float* attn  = slotA;                 // written by merge after qsel dead
    float* ctx   = (float*)d_ws;          // 16MB overlay, after merge

    qkv_proj_kernel<<<dim3(64, 4, 3), 256, 0, stream>>>(X, Wq, bq, Wk, bk, Wv, bv, qw, kw, vw);
    count_kernel<<<1, 256, 0, stream>>>(idxs, u_part, count);
    compact_kernel<<<1, 256, 0, stream>>>(count, klist, ncp);
    ksum_vmean_part_kernel<<<dim3(8, 32), 256, 0, stream>>>(count, kw, vw, kpart, vpart);
    ksum_vmean_reduce_kernel<<<32, 64, 0, stream>>>(kpart, vpart, ksum, vmean);
    sparsity_scan_kernel<<<dim3(16, 32), 256, 0, stream>>>(qw, kw, ksum, klist, ncp, spars);
    topk_kernel<<<32, 256, 0, stream>>>(spars, topi);
    gather_q_kernel<<<32, 256, 0, stream>>>(qw, topi, qsel);
    // qw dead; S/pvp take over that region.
    sel_scores_kernel<<<dim3(8, 32), 256, 0, stream>>>(qsel, kw, S);
    sel_softmax_kernel<<<1280, 256, 0, stream>>>(S);
    pv_part_kernel<<<dim3(16, 32), 256, 0, stream>>>(S, vw, pvp);
    pv_merge_kernel<<<32, 256, 0, stream>>>(pvp, attn);
    // S/pvp dead; ctx takes over the whole front region.
    ctx_fill_kernel<<<16384, 256, 0, stream>>>(vmean, ctx);
    ctx_scatter_kernel<<<dim3(USEL, BHEADS), 64, 0, stream>>>(attn, topi, ctx);
    out_proj_kernel<<<dim3(64, 4), 256, 0, stream>>>(ctx, Wo, bo, (float*)d_out);
}